// Round 9
// baseline (149.015 us; speedup 1.0000x reference)
//
#include <hip/hip_runtime.h>
#include <math.h>

// U=128, D=256, B=1024, E=64, H=8
// prep_kernel : f32 -> bf16 frag-tiled weights [n/16][k/32][16][32] + x/wqkv -> bf16
// fused_mfma  : per (u, 64-row batch tile): big GEMMs via MFMA with DIRECT global
//               B-fragment loads (reg double-buffered); fp32 tail; coalesced
//               enc/scores stores.
// attn_kernel : MFMA Q/K proj + per-head MFMA S + register softmax + column sums
// final/attnmean: outputs

typedef float f32x4 __attribute__((ext_vector_type(4)));
typedef int   i32x4 __attribute__((ext_vector_type(4)));

__device__ __forceinline__ void mfma_bf16(f32x4& c, i32x4 a, i32x4 b) {
    asm("v_mfma_f32_16x16x32_bf16 %0, %1, %2, %0" : "+v"(c) : "v"(a), "v"(b));
}

__device__ __forceinline__ void gl_lds16(const void* g, void* l) {
    __builtin_amdgcn_global_load_lds(
        (const __attribute__((address_space(1))) unsigned int*)g,
        (__attribute__((address_space(3))) unsigned int*)l, 16, 0, 0);
}

__device__ __forceinline__ unsigned short f2bf(float v) {
    union { __bf16 b; unsigned short u; } cv;
    cv.b = (__bf16)v;
    return cv.u;
}

// ---------------- prep: convert + frag-tile weights to bf16 ----------------
__global__ __launch_bounds__(256)
void prep_kernel(const float* __restrict__ W1, const float* __restrict__ W2,
                 const float* __restrict__ W3, const float* __restrict__ Wr,
                 const float* __restrict__ x, const float* __restrict__ Wqkv,
                 unsigned short* __restrict__ W1t, unsigned short* __restrict__ W2t,
                 unsigned short* __restrict__ W3t, unsigned short* __restrict__ Wrt,
                 unsigned short* __restrict__ xb, unsigned short* __restrict__ wqkvb)
{
    const int bid = blockIdx.x, t = threadIdx.x;
    if (bid >= 3456) {  // plain convert, no transpose
        const float* src; unsigned short* dst; int base;
        if (bid >= 3584) { src = Wqkv; dst = wqkvb; base = (bid - 3584) * 2048 + t * 8; }
        else             { src = x;    dst = xb;    base = (bid - 3456) * 2048 + t * 8; }
        const float4 v0 = *(const float4*)(src + base);
        const float4 v1 = *(const float4*)(src + base + 4);
        __align__(16) unsigned short o[8];
        o[0]=f2bf(v0.x); o[1]=f2bf(v0.y); o[2]=f2bf(v0.z); o[3]=f2bf(v0.w);
        o[4]=f2bf(v1.x); o[5]=f2bf(v1.y); o[6]=f2bf(v1.z); o[7]=f2bf(v1.w);
        *(uint4*)(dst + base) = *(const uint4*)o;
        return;
    }
    const float* src; unsigned short* dst; int u, k0, n0, N, ktiles;
    if (bid < 2048)      { u = bid >> 4;        int tl = bid & 15;       k0 = (tl>>2)*64; n0 = (tl&3)*64; N=256; ktiles=8; src = W1 + (size_t)u*65536; dst = W1t + (size_t)u*65536; }
    else if (bid < 3072) { int b2 = bid - 2048; u = b2 >> 3; int tl = b2 & 7; k0 = (tl>>1)*64; n0 = (tl&1)*64; N=128; ktiles=8; src = W2 + (size_t)u*32768; dst = W2t + (size_t)u*32768; }
    else if (bid < 3328) { int b3 = bid - 3072; u = b3 >> 1; int tl = b3 & 1; k0 = tl*64;      n0 = 0;         N=64;  ktiles=4; src = W3 + (size_t)u*8192;  dst = W3t + (size_t)u*8192;  }
    else                 { u = bid - 3328;      k0 = 0; n0 = 0;                                 N=64;  ktiles=2; src = Wr + (size_t)u*4096;  dst = Wrt + (size_t)u*4096;  }

    __shared__ unsigned short tile[64 * 65];
    #pragma unroll
    for (int i = 0; i < 16; ++i) {
        const int e = i * 256 + t;
        const int kk = e >> 6, nn = e & 63;
        tile[kk * 65 + nn] = f2bf(src[(size_t)(k0 + kk) * N + n0 + nn]);
    }
    __syncthreads();
    #pragma unroll
    for (int i = 0; i < 16; ++i) {
        const int e = i * 256 + t;
        const int nn = e >> 6, kk = e & 63;
        const int n = n0 + nn, k = k0 + kk;
        dst[(size_t)(((n >> 4) * ktiles + (k >> 5)) * 512 + (n & 15) * 32 + (k & 31))] = tile[kk * 65 + nn];
    }
}

// ---------------- fused universe chain ----------------
__global__ __launch_bounds__(256, 4)
void fused_mfma(const unsigned short* __restrict__ xb,
                const unsigned short* __restrict__ W1t, const unsigned short* __restrict__ W2t,
                const unsigned short* __restrict__ W3t, const unsigned short* __restrict__ Wrt,
                const float* __restrict__ fs, const float* __restrict__ dm,
                const float* __restrict__ b1, const float* __restrict__ g1, const float* __restrict__ be1,
                const float* __restrict__ b2, const float* __restrict__ g2, const float* __restrict__ be2,
                const float* __restrict__ b3, const float* __restrict__ br,
                const float* __restrict__ Wa1, const float* __restrict__ ba1,
                const float* __restrict__ Wa2, const float* __restrict__ ba2,
                const float* __restrict__ Wa3, const float* __restrict__ ba3,
                unsigned short* __restrict__ enc_bfg, float* __restrict__ scores_g)
{
    __shared__ __align__(128) char sm[39680];
    char* R0 = sm;
    float* pS = (float*)(sm + 36864);
    float* pQ = (float*)(sm + 37888);
    float2* rst = (float2*)(sm + 38912);
    float* dmis = (float*)(sm + 39424);

    const int t = threadIdx.x;
    const int wid = t >> 6, lane = t & 63, l15 = lane & 15, lk = lane >> 4;
    const int swz = (l15 & 7) << 4;
    const int lo64 = l15 * 64 + lk * 16;
    const int bx = blockIdx.x;
    const int xcd = bx & 7, idx = bx >> 3;
    const int u = ((idx >> 4) << 3) + xcd;
    const int b0 = (idx & 15) * 64;

    const float corru = fs[u] * 137.036f;
    const float dmu = dm[u];

    const char* xbase = (const char*)xb + (size_t)b0 * 512;
    const char* w1u = (const char*)W1t + (size_t)u * 131072;
    const char* w2u = (const char*)W2t + (size_t)u * 65536;
    const char* w3u = (const char*)W3t + (size_t)u * 16384;
    const char* wru = (const char*)Wrt + (size_t)u * 8192;

    #pragma unroll
    for (int it = 0; it < 8; ++it) {
        const int d = it * 4096 + t * 16;
        const int s = d ^ (((d >> 9) & 7) << 4);
        gl_lds16(xbase + s, R0 + it * 4096 + wid * 1024);
    }
    __syncthreads();  // B0

    // ===== GEMM1: [64][256] = A_x @ W1t, K=256, B direct + reg double-buffer =====
    const f32x4 z4 = {0.f, 0.f, 0.f, 0.f};
    f32x4 acc[4][4];
    #pragma unroll
    for (int mi = 0; mi < 4; ++mi)
        #pragma unroll
        for (int ni = 0; ni < 4; ++ni) acc[mi][ni] = z4;

    {
        i32x4 bfP[4], bfQ[4];
        #pragma unroll
        for (int ni = 0; ni < 4; ++ni)
            bfP[ni] = *(const i32x4*)(w1u + ((wid * 4 + ni) * 8 + 0) * 1024 + lo64);
        #pragma unroll
        for (int kt = 0; kt < 8; ++kt) {
            if (kt < 7) {
                #pragma unroll
                for (int ni = 0; ni < 4; ++ni)
                    ((kt & 1) ? bfP : bfQ)[ni] =
                        *(const i32x4*)(w1u + ((wid * 4 + ni) * 8 + kt + 1) * 1024 + lo64);
            }
            i32x4 af[4];
            const int p = kt >> 1, ks = kt & 1;
            #pragma unroll
            for (int mi = 0; mi < 4; ++mi) {
                const int off = ((mi * 16 + l15) << 9) + p * 128 + ks * 64 + lk * 16;
                af[mi] = *(const i32x4*)(R0 + (off ^ swz));
            }
            #pragma unroll
            for (int mi = 0; mi < 4; ++mi)
                #pragma unroll
                for (int ni = 0; ni < 4; ++ni)
                    mfma_bf16(acc[mi][ni], af[mi], ((kt & 1) ? bfQ : bfP)[ni]);
        }
    }

    // ===== LN1 + relu -> H1 bf16 [64][512B] swz =====
    float bb[4], gg[4], ee[4];
    #pragma unroll
    for (int ni = 0; ni < 4; ++ni) {
        const int c = wid * 64 + ni * 16 + l15;
        bb[ni] = b1[u * 256 + c]; gg[ni] = g1[u * 256 + c]; ee[ni] = be1[u * 256 + c];
    }
    #pragma unroll
    for (int mi = 0; mi < 4; ++mi) {
        #pragma unroll
        for (int j = 0; j < 4; ++j) {
            float s = 0.f, q = 0.f;
            #pragma unroll
            for (int ni = 0; ni < 4; ++ni) {
                const float h = acc[mi][ni][j] * corru + bb[ni];
                acc[mi][ni][j] = h;
                s += h; q += h * h;
            }
            #pragma unroll
            for (int m = 1; m < 16; m <<= 1) { s += __shfl_xor(s, m); q += __shfl_xor(q, m); }
            if (l15 == 0) {
                const int r = mi * 16 + lk * 4 + j;
                pS[wid * 64 + r] = s; pQ[wid * 64 + r] = q;
            }
        }
    }
    __syncthreads();  // B1
    if (t < 64) {
        const float s = pS[t] + pS[64 + t] + pS[128 + t] + pS[192 + t];
        const float q = pQ[t] + pQ[64 + t] + pQ[128 + t] + pQ[192 + t];
        const float mean = s * (1.f / 256.f);
        const float var = fmaxf(q * (1.f / 256.f) - mean * mean, 0.f);
        rst[t] = make_float2(mean, rsqrtf(var + 1e-5f));
    }
    __syncthreads();  // B2
    #pragma unroll
    for (int mi = 0; mi < 4; ++mi) {
        #pragma unroll
        for (int j = 0; j < 4; ++j) {
            const int r = mi * 16 + lk * 4 + j;
            const float2 st = rst[r];
            #pragma unroll
            for (int ni = 0; ni < 4; ++ni) {
                const float h = fmaxf((acc[mi][ni][j] - st.x) * st.y * gg[ni] + ee[ni], 0.f);
                const int c = wid * 64 + ni * 16 + l15;
                const int off = (r << 9) + c * 2;
                *(__bf16*)(R0 + (off ^ ((r & 7) << 4))) = (__bf16)h;
            }
        }
    }
    __syncthreads();  // B3: H1 ready

    // ===== GEMM2: [64][128] = H1 @ W2t, K=256, reg double-buffer =====
    f32x4 acc2[4][2];
    #pragma unroll
    for (int mi = 0; mi < 4; ++mi) { acc2[mi][0] = z4; acc2[mi][1] = z4; }
    {
        i32x4 bfP[2], bfQ[2];
        #pragma unroll
        for (int ni = 0; ni < 2; ++ni)
            bfP[ni] = *(const i32x4*)(w2u + ((wid * 2 + ni) * 8 + 0) * 1024 + lo64);
        #pragma unroll
        for (int kt = 0; kt < 8; ++kt) {
            if (kt < 7) {
                #pragma unroll
                for (int ni = 0; ni < 2; ++ni)
                    ((kt & 1) ? bfP : bfQ)[ni] =
                        *(const i32x4*)(w2u + ((wid * 2 + ni) * 8 + kt + 1) * 1024 + lo64);
            }
            i32x4 af[4];
            const int p = kt >> 1, ks = kt & 1;
            #pragma unroll
            for (int mi = 0; mi < 4; ++mi) {
                const int off = ((mi * 16 + l15) << 9) + p * 128 + ks * 64 + lk * 16;
                af[mi] = *(const i32x4*)(R0 + (off ^ swz));
            }
            #pragma unroll
            for (int mi = 0; mi < 4; ++mi)
                #pragma unroll
                for (int ni = 0; ni < 2; ++ni)
                    mfma_bf16(acc2[mi][ni], af[mi], ((kt & 1) ? bfQ : bfP)[ni]);
        }
    }

    // ===== LN2 + relu -> H2 bf16 [64][256B] at [0,16K) =====
    float bb2[2], gg2[2], ee2[2];
    #pragma unroll
    for (int ni = 0; ni < 2; ++ni) {
        const int c = wid * 32 + ni * 16 + l15;
        bb2[ni] = b2[u * 128 + c]; gg2[ni] = g2[u * 128 + c]; ee2[ni] = be2[u * 128 + c];
    }
    #pragma unroll
    for (int mi = 0; mi < 4; ++mi) {
        #pragma unroll
        for (int j = 0; j < 4; ++j) {
            float s = 0.f, q = 0.f;
            #pragma unroll
            for (int ni = 0; ni < 2; ++ni) {
                const float h = acc2[mi][ni][j] + bb2[ni];
                acc2[mi][ni][j] = h;
                s += h; q += h * h;
            }
            #pragma unroll
            for (int m = 1; m < 16; m <<= 1) { s += __shfl_xor(s, m); q += __shfl_xor(q, m); }
            if (l15 == 0) {
                const int r = mi * 16 + lk * 4 + j;
                pS[wid * 64 + r] = s; pQ[wid * 64 + r] = q;
            }
        }
    }
    __syncthreads();  // B4
    if (t < 64) {
        const float s = pS[t] + pS[64 + t] + pS[128 + t] + pS[192 + t];
        const float q = pQ[t] + pQ[64 + t] + pQ[128 + t] + pQ[192 + t];
        const float mean = s * (1.f / 128.f);
        const float var = fmaxf(q * (1.f / 128.f) - mean * mean, 0.f);
        rst[t] = make_float2(mean, rsqrtf(var + 1e-5f));
    }
    __syncthreads();  // B5
    #pragma unroll
    for (int mi = 0; mi < 4; ++mi) {
        #pragma unroll
        for (int j = 0; j < 4; ++j) {
            const int r = mi * 16 + lk * 4 + j;
            const float2 st = rst[r];
            #pragma unroll
            for (int ni = 0; ni < 2; ++ni) {
                const float h = fmaxf((acc2[mi][ni][j] - st.x) * st.y * gg2[ni] + ee2[ni], 0.f);
                const int c = wid * 32 + ni * 16 + l15;
                const int off = (r << 8) + c * 2;
                *(__bf16*)(R0 + (off ^ ((r & 7) << 4))) = (__bf16)h;
            }
        }
    }
    __syncthreads();  // B6: H2 ready

    // ===== GEMM3: enc [64][64] = H2 @ W3t, K=128 =====
    f32x4 acc3[4];
    #pragma unroll
    for (int mi = 0; mi < 4; ++mi) acc3[mi] = z4;
    #pragma unroll
    for (int ks = 0; ks < 4; ++ks) {
        const i32x4 bfr = *(const i32x4*)(w3u + (wid * 4 + ks) * 1024 + lo64);
        #pragma unroll
        for (int mi = 0; mi < 4; ++mi) {
            const int off = ((mi * 16 + l15) << 8) + ks * 64 + lk * 16;
            const i32x4 afm = *(const i32x4*)(R0 + (off ^ swz));
            mfma_bf16(acc3[mi], afm, bfr);
        }
    }
    // epilogue: +b3 (f32 encr regs), sumsq partials (global store moved post-B8)
    const int c16 = wid * 16 + l15;
    const float b3v = b3[u * 64 + c16];
    float encr[4][4];
    #pragma unroll
    for (int mi = 0; mi < 4; ++mi) {
        #pragma unroll
        for (int j = 0; j < 4; ++j) {
            const float e = acc3[mi][j] + b3v;
            encr[mi][j] = e;
            float q = e * e;
            #pragma unroll
            for (int m = 1; m < 16; m <<= 1) q += __shfl_xor(q, m);
            if (l15 == 0) {
                const int r = mi * 16 + lk * 4 + j;
                pQ[wid * 64 + r] = q;
            }
        }
    }
    __syncthreads();  // B7: all GEMM3 H2-reads done, partials visible
    if (t < 64) {
        const float q = pQ[t] + pQ[64 + t] + pQ[128 + t] + pQ[192 + t];
        dmis[t] = tanhf(dmu * q);
    }
    // enc bf16 -> [0,8192) (old H2 low half, dead after B7)
    #pragma unroll
    for (int mi = 0; mi < 4; ++mi) {
        #pragma unroll
        for (int j = 0; j < 4; ++j) {
            const int r = mi * 16 + lk * 4 + j;
            const int off = (r << 7) + c16 * 2;
            *(__bf16*)(R0 + (off ^ ((r & 7) << 4))) = (__bf16)encr[mi][j];
        }
    }
    __syncthreads();  // B8: enc + dmis ready

    // coalesced enc global store from LDS: 8 rows x 128B per wave-store, line-aligned
    {
        const int c8 = t & 7;
        #pragma unroll
        for (int pass = 0; pass < 2; ++pass) {
            const int row = pass * 32 + (t >> 3);
            const int off = (row << 7) + c8 * 16;
            const uint4 v = *(const uint4*)(R0 + (off ^ ((row & 7) << 4)));
            *(uint4*)((char*)enc_bfg + (((size_t)(b0 + row) * 128 + u) << 7) + c8 * 16) = v;
        }
    }

    // ===== Wr: re [64][64] = enc_bf @ Wrt, K=64; z f32 -> [8192,25600) =====
    f32x4 accR[4];
    #pragma unroll
    for (int mi = 0; mi < 4; ++mi) accR[mi] = z4;
    #pragma unroll
    for (int ks = 0; ks < 2; ++ks) {
        const i32x4 bfr = *(const i32x4*)(wru + (wid * 2 + ks) * 1024 + lo64);
        #pragma unroll
        for (int mi = 0; mi < 4; ++mi) {
            const int off = ((mi * 16 + l15) << 7) + ks * 64 + lk * 16;
            const i32x4 afm = *(const i32x4*)(R0 + (off ^ swz));
            mfma_bf16(accR[mi], afm, bfr);
        }
    }
    const float brv = br[u * 64 + c16];
    #pragma unroll
    for (int mi = 0; mi < 4; ++mi) {
        #pragma unroll
        for (int j = 0; j < 4; ++j) {
            const int r = mi * 16 + lk * 4 + j;
            const float zv = accR[mi][j] + brv + dmis[r] * encr[mi][j];
            *(float*)(R0 + 8192 + r * 272 + c16 * 4) = zv;
        }
    }
    __syncthreads();  // B9: z ready, enc reads done

    #pragma unroll
    for (int it = 0; it < 2; ++it)
        gl_lds16((const char*)Wa1 + (size_t)u * 8192 + it * 4096 + t * 16,
                 R0 + it * 4096 + wid * 1024);
    if (t < 128)
        gl_lds16((const char*)Wa2 + (size_t)u * 2048 + t * 16, R0 + 25600 + wid * 1024);
    if (t < 16) ((float*)(R0 + 27648))[t] = Wa3[u * 16 + t];
    if (t == 16) ((float*)(R0 + 27648))[16] = ba3[u];
    __syncthreads();  // B10

    {
        const int row = t >> 2, g4 = t & 3;
        float accA[8] = {0.f,0.f,0.f,0.f,0.f,0.f,0.f,0.f};
        const float* zrow = (const float*)(R0 + 8192 + row * 272);
        const float* wa1s = (const float*)R0;
        for (int k = 0; k < 64; ++k) {
            const float zv = zrow[k];
            const float4 wA = *(const float4*)(wa1s + k * 32 + g4 * 8);
            const float4 wB = *(const float4*)(wa1s + k * 32 + g4 * 8 + 4);
            accA[0] += zv * wA.x; accA[1] += zv * wA.y; accA[2] += zv * wA.z; accA[3] += zv * wA.w;
            accA[4] += zv * wB.x; accA[5] += zv * wB.y; accA[6] += zv * wB.z; accA[7] += zv * wB.w;
        }
        const float4 bA = *(const float4*)(ba1 + u * 32 + g4 * 8);
        const float4 bB = *(const float4*)(ba1 + u * 32 + g4 * 8 + 4);
        float* a1s = (float*)(R0 + 28160);
        a1s[row * 34 + g4 * 8 + 0] = fmaxf(accA[0] + bA.x, 0.f);
        a1s[row * 34 + g4 * 8 + 1] = fmaxf(accA[1] + bA.y, 0.f);
        a1s[row * 34 + g4 * 8 + 2] = fmaxf(accA[2] + bA.z, 0.f);
        a1s[row * 34 + g4 * 8 + 3] = fmaxf(accA[3] + bA.w, 0.f);
        a1s[row * 34 + g4 * 8 + 4] = fmaxf(accA[4] + bB.x, 0.f);
        a1s[row * 34 + g4 * 8 + 5] = fmaxf(accA[5] + bB.y, 0.f);
        a1s[row * 34 + g4 * 8 + 6] = fmaxf(accA[6] + bB.z, 0.f);
        a1s[row * 34 + g4 * 8 + 7] = fmaxf(accA[7] + bB.w, 0.f);
    }
    __syncthreads();  // B11

    {
        const int row = t >> 2, g4 = t & 3;
        const float* a1s = (const float*)(R0 + 28160);
        const float* wa2s = (const float*)(R0 + 25600);
        float accB[4] = {0.f,0.f,0.f,0.f};
        for (int k = 0; k < 32; ++k) {
            const float av = a1s[row * 34 + k];
            const float4 w = *(const float4*)(wa2s + k * 16 + g4 * 4);
            accB[0] += av * w.x; accB[1] += av * w.y; accB[2] += av * w.z; accB[3] += av * w.w;
        }
        const float4 bB = *(const float4*)(ba2 + u * 16 + g4 * 4);
        float* a2s = (float*)R0;
        a2s[row * 18 + g4 * 4 + 0] = fmaxf(accB[0] + bB.x, 0.f);
        a2s[row * 18 + g4 * 4 + 1] = fmaxf(accB[1] + bB.y, 0.f);
        a2s[row * 18 + g4 * 4 + 2] = fmaxf(accB[2] + bB.z, 0.f);
        a2s[row * 18 + g4 * 4 + 3] = fmaxf(accB[3] + bB.w, 0.f);
    }
    __syncthreads();  // B12

    if (t < 64) {
        const float* a2s = (const float*)R0;
        const float* w3s = (const float*)(R0 + 27648);
        float a = w3s[16];
        #pragma unroll
        for (int k = 0; k < 16; ++k) a += a2s[t * 18 + k] * w3s[k];
        // scores in [u][B] layout: 64 contiguous floats per block
        scores_g[(size_t)u * 1024 + b0 + t] = 1.f / (1.f + __expf(-a));
    }
}

// ---------------- attention: MFMA proj + per-head MFMA S + register softmax ----------------
__global__ __launch_bounds__(256, 3)
void attn_kernel(const unsigned short* __restrict__ enc_bf,
                 const unsigned short* __restrict__ wqkv_bf,
                 const float* __restrict__ bqkv, float* __restrict__ smean,
                 float* __restrict__ bpart)
{
    __shared__ __align__(128) char sm[34944];
    char* Qp = sm;
    char* Ks = sm + 16384;
    float* colp = (float*)(sm + 32832);
    char* ENCs = sm;
    char* WQs  = sm + 16384;

    const int t = threadIdx.x;
    const int wid = t >> 6, lane = t & 63, l15 = lane & 15, lk = lane >> 4;
    const int swz = (l15 & 7) << 4;
    const int b = blockIdx.x;

    const char* eb = (const char*)(enc_bf + (size_t)b * 8192);
    #pragma unroll
    for (int it = 0; it < 4; ++it) {
        const int d = it * 4096 + t * 16;
        const int s = d ^ (((d >> 7) & 7) << 4);
        gl_lds16(eb + s, ENCs + it * 4096 + wid * 1024);
    }
    const char* wb = (const char*)wqkv_bf;
    #pragma unroll
    for (int it = 0; it < 4; ++it) {
        const int d = it * 4096 + t * 16;
        const int s = d ^ (((d >> 7) & 7) << 4);
        gl_lds16(wb + s, WQs + it * 4096 + wid * 1024);
    }
    __syncthreads();

    // ===== proj: Q,K [128][64] = enc @ Wqkv^T =====
    const f32x4 z4 = {0.f,0.f,0.f,0.f};
    f32x4 aq[2][4], ak[2][4];
    #pragma unroll
    for (int mi = 0; mi < 2; ++mi)
        #pragma unroll
        for (int ni = 0; ni < 4; ++ni) { aq[mi][ni] = z4; ak[mi][ni] = z4; }

    i32x4 af[2][2];
    #pragma unroll
    for (int mi = 0; mi < 2; ++mi)
        #pragma unroll
        for (int ks = 0; ks < 2; ++ks) {
            const int off = ((wid * 32 + mi * 16 + l15) << 7) + ks * 64 + lk * 16;
            af[mi][ks] = *(const i32x4*)(ENCs + (off ^ swz));
        }
    #pragma unroll
    for (int ni = 0; ni < 4; ++ni)
        #pragma unroll
        for (int ks = 0; ks < 2; ++ks) {
            const int offq = ((ni * 16 + l15) << 7) + ks * 64 + lk * 16;
            const i32x4 bq = *(const i32x4*)(WQs + (offq ^ swz));
            mfma_bf16(aq[0][ni], af[0][ks], bq);
            mfma_bf16(aq[1][ni], af[1][ks], bq);
            const i32x4 bk = *(const i32x4*)(WQs + ((offq + 8192) ^ swz));
            mfma_bf16(ak[0][ni], af[0][ks], bk);
            mfma_bf16(ak[1][ni], af[1][ks], bk);
        }

    float bqv[4], bkv[4];
    #pragma unroll
    for (int ni = 0; ni < 4; ++ni) {
        bqv[ni] = bqkv[ni * 16 + l15];
        bkv[ni] = bqkv[64 + ni * 16 + l15];
    }
    __syncthreads();  // proj LDS reads complete in all waves

    // zero Qp pads (dims 8..31 of each of 2*128 rows)
    {
        const int par = t >> 7, row = t & 127;
        char* base = Qp + par * 8192 + row * 64;
        *(f32x4*)(base + 16) = z4;
        *(f32x4*)(base + 32) = z4;
        *(f32x4*)(base + 48) = z4;
    }
    // write K full [128][64] swz
    #pragma unroll
    for (int mi = 0; mi < 2; ++mi)
        #pragma unroll
        for (int ni = 0; ni < 4; ++ni)
            #pragma unroll
            for (int j = 0; j < 4; ++j) {
                const int row = wid * 32 + mi * 16 + lk * 4 + j;
                const int f = ni * 16 + l15;
                const int off = row * 128 + f * 2;
                *(__bf16*)(Ks + (off ^ ((row & 7) << 4))) = (__bf16)(ak[mi][ni][j] + bkv[ni]);
            }
    __syncthreads();  // Ks + pads ready

    const float qscale = 0.35355339059327373f;  // 1/sqrt(8)
    float cp[8] = {0.f,0.f,0.f,0.f,0.f,0.f,0.f,0.f};

    #pragma unroll
    for (int p = 0; p < 4; ++p) {
        #pragma unroll
        for (int mi = 0; mi < 2; ++mi)
            #pragma unroll
            for (int j = 0; j < 4; ++j) {
                const int row = wid * 32 + mi * 16 + lk * 4 + j;
                *(__bf16*)(Qp + (l15 >> 3) * 8192 + row * 64 + (l15 & 7) * 2) =
                    (__bf16)((aq[mi][p][j] + bqv[p]) * qscale);
            }
        __syncthreads();  // pack visible

        #pragma unroll 1
        for (int par = 0; par < 2; ++par) {
            const int h = p * 2 + par;
            const i32x4 aQ0 = *(const i32x4*)(Qp + par * 8192 + (wid * 32 + l15) * 64 + lk * 16);
            const i32x4 aQ1 = *(const i32x4*)(Qp + par * 8192 + (wid * 32 + 16 + l15) * 64 + lk * 16);
            f32x4 accS[2][8];
            #pragma unroll
            for (int ci = 0; ci < 8; ++ci) { accS[0][ci] = z4; accS[1][ci] = z4; }
            #pragma unroll
            for (int ci = 0; ci < 8; ++ci) {
                const int col = ci * 16 + l15;
                // wrapped in-row head block: k>=8 lanes read real finite K data,
                // zeroed by A pads (round-7 NaN fix)
                const i32x4 bK = *(const i32x4*)(Ks + ((col * 128 + ((h + lk) & 7) * 16) ^ ((col & 7) << 4)));
                mfma_bf16(accS[0][ci], aQ0, bK);
                mfma_bf16(accS[1][ci], aQ1, bK);
            }
            #pragma unroll
            for (int mi = 0; mi < 2; ++mi)
                #pragma unroll
                for (int j = 0; j < 4; ++j) {
                    float e[8];
                    float z = 0.f;
                    #pragma unroll
                    for (int ci = 0; ci < 8; ++ci) { e[ci] = __expf(accS[mi][ci][j]); z += e[ci]; }
                    z += __shfl_xor(z, 1); z += __shfl_xor(z, 2);
                    z += __shfl_xor(z, 4); z += __shfl_xor(z, 8);
                    const float zi = 1.f / z;
                    #pragma unroll
                    for (int ci = 0; ci < 8; ++ci) cp[ci] += e[ci] * zi;
                }
        }
        __syncthreads();  // S reads done before next pack overwrites Qp
    }

    #pragma unroll
    for (int ci = 0; ci < 8; ++ci) {
        cp[ci] += __shfl_xor(cp[ci], 16);
        cp[ci] += __shfl_xor(cp[ci], 32);
    }
    if (lk == 0) {
        #pragma unroll
        for (int ci = 0; ci < 8; ++ci)
            colp[wid * 128 + ci * 16 + l15] = cp[ci];
    }
    __syncthreads();
    float v = 0.f;
    if (t < 128) {
        v = colp[t] + colp[128 + t] + colp[256 + t] + colp[384 + t];
        smean[(size_t)b * 128 + t] = v * (1.f / 1024.f);
    }
    #pragma unroll
    for (int m = 1; m < 64; m <<= 1) v += __shfl_xor(v, m);
    if (lane == 0) colp[512 + wid] = v;
    __syncthreads();
    if (t == 0)
        bpart[b] = (colp[512] + colp[513] + colp[514] + colp[515]) * (1.f / 1024.f);
}

__global__ __launch_bounds__(64)
void final_kernel(const float* __restrict__ scores_g, const float* __restrict__ smean,
                  const float* __restrict__ Wc1, const float* __restrict__ bc1,
                  const float* __restrict__ Wc2, const float* __restrict__ bc2,
                  const float* __restrict__ Wc3, const float* __restrict__ bc3,
                  float* __restrict__ out)
{
    __shared__ float sc[128];
    __shared__ float c1[64];
    __shared__ float c2[32];
    const int b = blockIdx.x, t = threadIdx.x;
    // scores now [u][B]
    const float s0 = scores_g[(size_t)t * 1024 + b];
    const float s1 = scores_g[(size_t)(t + 64) * 1024 + b];
    sc[t] = s0; sc[64 + t] = s1;
    const float v0 = smean[(size_t)b * 128 + t];
    const float v1 = smean[(size_t)b * 128 + 64 + t];
    __syncthreads();
    float a = bc1[t];
    #pragma unroll 8
    for (int i = 0; i < 128; ++i) a += sc[i] * Wc1[i * 64 + t];
    c1[t] = fmaxf(a, 0.f);
    __syncthreads();
    if (t < 32) {
        float a2 = bc2[t];
        #pragma unroll 8
        for (int i = 0; i < 64; ++i) a2 += c1[i] * Wc2[i * 32 + t];
        c2[t] = fmaxf(a2, 0.f);
    }
    __syncthreads();
    float p = (t < 32) ? c2[t] * Wc3[t] : 0.f;
    #pragma unroll
    for (int m = 1; m < 64; m <<= 1) p += __shfl_xor(p, m);
    const float cons = 1.f / (1.f + __expf(-(p + bc3[0])));

    float sum = s0 + s1;
    float sq  = s0 * s0 + s1 * s1;
    float wsm = s0 * v0 + s1 * v1;
    float na  = (s0 > 0.1f ? 1.f : 0.f) + (s1 > 0.1f ? 1.f : 0.f);
    #pragma unroll
    for (int m = 1; m < 64; m <<= 1) {
        sum += __shfl_xor(sum, m); sq += __shfl_xor(sq, m);
        wsm += __shfl_xor(wsm, m); na += __shfl_xor(na, m);
    }
    if (t == 0) {
        const float mean = sum * (1.f / 128.f);
        float var = (sq - 128.f * mean * mean) * (1.f / 127.f);
        var = fmaxf(var, 0.f);
        const float agree = 1.f - sqrtf(var) / (mean + 1e-8f);
        out[b]        = cons * wsm;
        out[1024 + b] = (cons > 0.95f) ? 1.f : 0.f;
        out[2048 + b] = agree;
        out[3072 + b] = cons;
        out[4097 + b] = na;
    }
}

__global__ __launch_bounds__(256)
void attnmean_kernel(const float* __restrict__ bpart, float* __restrict__ out)
{
    __shared__ float red[4];
    const int t = threadIdx.x;
    const int lane = t & 63, wid = t >> 6;
    float s = bpart[t] + bpart[256 + t] + bpart[512 + t] + bpart[768 + t];
    #pragma unroll
    for (int m = 1; m < 64; m <<= 1) s += __shfl_xor(s, m);
    if (lane == 0) red[wid] = s;
    __syncthreads();
    if (t == 0) out[4096] = (red[0] + red[1] + red[2] + red[3]) * (1.f / 131072.f);
}

extern "C" void kernel_launch(void* const* d_in, const int* in_sizes, int n_in,
                              void* d_out, int out_size, void* d_ws, size_t ws_size,
                              hipStream_t stream)
{
    const float* x    = (const float*)d_in[0];
    const float* fs   = (const float*)d_in[1];
    const float* dm   = (const float*)d_in[2];
    const float* W1   = (const float*)d_in[3];
    const float* b1   = (const float*)d_in[4];
    const float* g1   = (const float*)d_in[5];
    const float* be1  = (const float*)d_in[6];
    const float* W2   = (const float*)d_in[7];
    const float* b2   = (const float*)d_in[8];
    const float* g2   = (const float*)d_in[9];
    const float* be2  = (const float*)d_in[10];
    const float* W3   = (const float*)d_in[11];
    const float* b3   = (const float*)d_in[12];
    const float* Wr   = (const float*)d_in[13];
    const float* br   = (const float*)d_in[14];
    const float* Wa1  = (const float*)d_in[15];
    const float* ba1  = (const float*)d_in[16];
    const float* Wa2  = (const float*)d_in[17];
    const float* ba2  = (const float*)d_in[18];
    const float* Wa3  = (const float*)d_in[19];
    const float* ba3  = (const float*)d_in[20];
    const float* Wqkv = (const float*)d_in[21];
    const float* bqkv = (const float*)d_in[22];
    // d_in[23]=Wo, d_in[24]=bo unused downstream
    const float* Wc1  = (const float*)d_in[25];
    const float* bc1  = (const float*)d_in[26];
    const float* Wc2  = (const float*)d_in[27];
    const float* bc2  = (const float*)d_in[28];
    const float* Wc3  = (const float*)d_in[29];
    const float* bc3  = (const float*)d_in[30];

    float* out = (float*)d_out;
    char*  ws8 = (char*)d_ws;
    unsigned short* enc_bf = (unsigned short*)ws8;             // 16 MB
    float* scores = (float*)(ws8 + 16777216);                  // 512 KB  [u][B]
    float* smean  = (float*)(ws8 + 17301504);                  // 512 KB
    float* bpart  = (float*)(ws8 + 17825792);                  // 4 KB
    unsigned short* xb    = (unsigned short*)(ws8 + 17829888); // 512 KB
    unsigned short* W1t   = (unsigned short*)(ws8 + 18354176); // 16 MB
    unsigned short* W2t   = (unsigned short*)(ws8 + 35131392); // 8 MB
    unsigned short* W3t   = (unsigned short*)(ws8 + 43520000); // 2 MB
    unsigned short* Wrt   = (unsigned short*)(ws8 + 45617152); // 1 MB
    unsigned short* wqkvb = (unsigned short*)(ws8 + 46665728); // 16 KB

    prep_kernel<<<3588, 256, 0, stream>>>(W1, W2, W3, Wr, x, Wqkv,
                                          W1t, W2t, W3t, Wrt, xb, wqkvb);
    fused_mfma<<<2048, 256, 0, stream>>>(xb, W1t, W2t, W3t, Wrt, fs, dm,
                                         b1, g1, be1, b2, g2, be2, b3, br,
                                         Wa1, ba1, Wa2, ba2, Wa3, ba3,
                                         enc_bf, scores);
    attn_kernel<<<1024, 256, 0, stream>>>(enc_bf, wqkvb, bqkv, smean, bpart);
    final_kernel<<<1024, 64, 0, stream>>>(scores, smean, Wc1, bc1, Wc2, bc2, Wc3, bc3, out);
    attnmean_kernel<<<1, 256, 0, stream>>>(bpart, out);
}

// Round 10
// 121.853 us; speedup vs baseline: 1.2229x; 1.2229x over previous
//
#include <hip/hip_runtime.h>
#include <math.h>

// U=128, D=256, B=1024, E=64, H=8
// prep_kernel : f32 -> bf16 frag-tiled weights [n/16][k/32][16][32] + x/wqkv -> bf16
//               + Wa1/Wa2 hi/lo bf16-split frag-tiled planes
// fused_mfma  : big GEMMs via MFMA with DIRECT global B-fragments; LN reductions
//               via DPP (VALU, no LDS); tail via split-bf16 MFMA (fp32-accurate).
// attn_kernel : MFMA Q/K proj + per-head MFMA S + DPP softmax + column sums
// final/attnmean: outputs

typedef float f32x4 __attribute__((ext_vector_type(4)));
typedef int   i32x4 __attribute__((ext_vector_type(4)));

__device__ __forceinline__ void mfma_bf16(f32x4& c, i32x4 a, i32x4 b) {
    asm("v_mfma_f32_16x16x32_bf16 %0, %1, %2, %0" : "+v"(c) : "v"(a), "v"(b));
}

__device__ __forceinline__ void gl_lds16(const void* g, void* l) {
    __builtin_amdgcn_global_load_lds(
        (const __attribute__((address_space(1))) unsigned int*)g,
        (__attribute__((address_space(3))) unsigned int*)l, 16, 0, 0);
}

__device__ __forceinline__ unsigned short f2bf(float v) {
    union { __bf16 b; unsigned short u; } cv;
    cv.b = (__bf16)v;
    return cv.u;
}
__device__ __forceinline__ float bf2f(unsigned short u) {
    union { unsigned int i; float f; } c; c.i = (unsigned int)u << 16; return c.f;
}

// sum over each 16-lane group via DPP (pure VALU, no LDS pipe):
// xor1 (quad_perm 1,0,3,2) + xor2 (quad_perm 2,3,0,1) + row_ror:4 + row_ror:8
__device__ __forceinline__ float red16(float v) {
    int x;
    x = __builtin_amdgcn_update_dpp(0, __float_as_int(v), 0xB1, 0xF, 0xF, true);
    v += __int_as_float(x);
    x = __builtin_amdgcn_update_dpp(0, __float_as_int(v), 0x4E, 0xF, 0xF, true);
    v += __int_as_float(x);
    x = __builtin_amdgcn_update_dpp(0, __float_as_int(v), 0x124, 0xF, 0xF, true);
    v += __int_as_float(x);
    x = __builtin_amdgcn_update_dpp(0, __float_as_int(v), 0x128, 0xF, 0xF, true);
    v += __int_as_float(x);
    return v;
}

// ---------------- prep: convert + frag-tile weights to bf16 ----------------
__global__ __launch_bounds__(256)
void prep_kernel(const float* __restrict__ W1, const float* __restrict__ W2,
                 const float* __restrict__ W3, const float* __restrict__ Wr,
                 const float* __restrict__ Wa1, const float* __restrict__ Wa2,
                 const float* __restrict__ x, const float* __restrict__ Wqkv,
                 unsigned short* __restrict__ W1t, unsigned short* __restrict__ W2t,
                 unsigned short* __restrict__ W3t, unsigned short* __restrict__ Wrt,
                 unsigned short* __restrict__ Wa1t, unsigned short* __restrict__ Wa2t,
                 unsigned short* __restrict__ xb, unsigned short* __restrict__ wqkvb)
{
    const int bid = blockIdx.x, t = threadIdx.x;
    if (bid >= 3588) {  // Wa1/Wa2 hi/lo split + frag-tile, one u per block
        const int uu = bid - 3588;
        #pragma unroll
        for (int i = 0; i < 8; ++i) {
            const int e = t * 8 + i;            // 0..2047
            const int k = e >> 5, n = e & 31;   // Wa1 [64 k][32 n]
            const float v = Wa1[(size_t)uu * 2048 + k * 32 + n];
            const unsigned short h = f2bf(v);
            const unsigned short l = f2bf(v - bf2f(h));
            const size_t d = (size_t)uu * 4096 +
                (((n >> 4) * 2 + (k >> 5)) * 512 + (n & 15) * 32 + (k & 31));
            Wa1t[d] = h; Wa1t[d + 2048] = l;
        }
        #pragma unroll
        for (int i = 0; i < 2; ++i) {
            const int e = t * 2 + i;            // 0..511
            const int k = e >> 4, n = e & 15;   // Wa2 [32 k][16 n]
            const float v = Wa2[(size_t)uu * 512 + k * 16 + n];
            const unsigned short h = f2bf(v);
            const unsigned short l = f2bf(v - bf2f(h));
            const size_t d = (size_t)uu * 1024 + n * 32 + k;
            Wa2t[d] = h; Wa2t[d + 512] = l;
        }
        return;
    }
    if (bid >= 3456) {  // plain convert, no transpose
        const float* src; unsigned short* dst; int base;
        if (bid >= 3584) { src = Wqkv; dst = wqkvb; base = (bid - 3584) * 2048 + t * 8; }
        else             { src = x;    dst = xb;    base = (bid - 3456) * 2048 + t * 8; }
        const float4 v0 = *(const float4*)(src + base);
        const float4 v1 = *(const float4*)(src + base + 4);
        __align__(16) unsigned short o[8];
        o[0]=f2bf(v0.x); o[1]=f2bf(v0.y); o[2]=f2bf(v0.z); o[3]=f2bf(v0.w);
        o[4]=f2bf(v1.x); o[5]=f2bf(v1.y); o[6]=f2bf(v1.z); o[7]=f2bf(v1.w);
        *(uint4*)(dst + base) = *(const uint4*)o;
        return;
    }
    const float* src; unsigned short* dst; int u, k0, n0, N, ktiles;
    if (bid < 2048)      { u = bid >> 4;        int tl = bid & 15;       k0 = (tl>>2)*64; n0 = (tl&3)*64; N=256; ktiles=8; src = W1 + (size_t)u*65536; dst = W1t + (size_t)u*65536; }
    else if (bid < 3072) { int b2 = bid - 2048; u = b2 >> 3; int tl = b2 & 7; k0 = (tl>>1)*64; n0 = (tl&1)*64; N=128; ktiles=8; src = W2 + (size_t)u*32768; dst = W2t + (size_t)u*32768; }
    else if (bid < 3328) { int b3 = bid - 3072; u = b3 >> 1; int tl = b3 & 1; k0 = tl*64;      n0 = 0;         N=64;  ktiles=4; src = W3 + (size_t)u*8192;  dst = W3t + (size_t)u*8192;  }
    else                 { u = bid - 3328;      k0 = 0; n0 = 0;                                 N=64;  ktiles=2; src = Wr + (size_t)u*4096;  dst = Wrt + (size_t)u*4096;  }

    __shared__ unsigned short tile[64 * 65];
    #pragma unroll
    for (int i = 0; i < 16; ++i) {
        const int e = i * 256 + t;
        const int kk = e >> 6, nn = e & 63;
        tile[kk * 65 + nn] = f2bf(src[(size_t)(k0 + kk) * N + n0 + nn]);
    }
    __syncthreads();
    #pragma unroll
    for (int i = 0; i < 16; ++i) {
        const int e = i * 256 + t;
        const int nn = e >> 6, kk = e & 63;
        const int n = n0 + nn, k = k0 + kk;
        dst[(size_t)(((n >> 4) * ktiles + (k >> 5)) * 512 + (n & 15) * 32 + (k & 31))] = tile[kk * 65 + nn];
    }
}

// ---------------- fused universe chain ----------------
__global__ __launch_bounds__(256, 4)
void fused_mfma(const unsigned short* __restrict__ xb,
                const unsigned short* __restrict__ W1t, const unsigned short* __restrict__ W2t,
                const unsigned short* __restrict__ W3t, const unsigned short* __restrict__ Wrt,
                const unsigned short* __restrict__ Wa1t, const unsigned short* __restrict__ Wa2t,
                const float* __restrict__ fs, const float* __restrict__ dm,
                const float* __restrict__ b1, const float* __restrict__ g1, const float* __restrict__ be1,
                const float* __restrict__ b2, const float* __restrict__ g2, const float* __restrict__ be2,
                const float* __restrict__ b3, const float* __restrict__ br,
                const float* __restrict__ ba1, const float* __restrict__ ba2,
                const float* __restrict__ Wa3, const float* __restrict__ ba3,
                unsigned short* __restrict__ enc_bfg, float* __restrict__ scores_g)
{
    // LDS: [0,32768) A_x/H1 -> H2 [0,16K) -> enc [0,8K) ; z_hi [8192,16384),
    // z_lo [16384,24576) ; a1_hi [24576,28672), a1_lo [28672,32768) ;
    // stats at [36864,39680)
    __shared__ __align__(128) char sm[39680];
    char* R0 = sm;
    float* pS = (float*)(sm + 36864);
    float* pQ = (float*)(sm + 37888);
    float2* rst = (float2*)(sm + 38912);
    float* dmis = (float*)(sm + 39424);

    const int t = threadIdx.x;
    const int wid = t >> 6, lane = t & 63, l15 = lane & 15, lk = lane >> 4;
    const int swz = (l15 & 7) << 4;
    const int lo64 = l15 * 64 + lk * 16;
    const int bx = blockIdx.x;
    const int xcd = bx & 7, idx = bx >> 3;
    const int u = ((idx >> 4) << 3) + xcd;
    const int b0 = (idx & 15) * 64;

    const float corru = fs[u] * 137.036f;
    const float dmu = dm[u];

    const char* xbase = (const char*)xb + (size_t)b0 * 512;
    const char* w1u = (const char*)W1t + (size_t)u * 131072;
    const char* w2u = (const char*)W2t + (size_t)u * 65536;
    const char* w3u = (const char*)W3t + (size_t)u * 16384;
    const char* wru = (const char*)Wrt + (size_t)u * 8192;
    const char* wa1u = (const char*)Wa1t + (size_t)u * 8192;
    const char* wa2u = (const char*)Wa2t + (size_t)u * 2048;

    #pragma unroll
    for (int it = 0; it < 8; ++it) {
        const int d = it * 4096 + t * 16;
        const int s = d ^ (((d >> 9) & 7) << 4);
        gl_lds16(xbase + s, R0 + it * 4096 + wid * 1024);
    }
    __syncthreads();  // B0

    // ===== GEMM1: [64][256] = A_x @ W1t, K=256, B direct + reg double-buffer =====
    const f32x4 z4 = {0.f, 0.f, 0.f, 0.f};
    f32x4 acc[4][4];
    #pragma unroll
    for (int mi = 0; mi < 4; ++mi)
        #pragma unroll
        for (int ni = 0; ni < 4; ++ni) acc[mi][ni] = z4;

    {
        i32x4 bfP[4], bfQ[4];
        #pragma unroll
        for (int ni = 0; ni < 4; ++ni)
            bfP[ni] = *(const i32x4*)(w1u + ((wid * 4 + ni) * 8 + 0) * 1024 + lo64);
        #pragma unroll
        for (int kt = 0; kt < 8; ++kt) {
            if (kt < 7) {
                #pragma unroll
                for (int ni = 0; ni < 4; ++ni)
                    ((kt & 1) ? bfP : bfQ)[ni] =
                        *(const i32x4*)(w1u + ((wid * 4 + ni) * 8 + kt + 1) * 1024 + lo64);
            }
            i32x4 af[4];
            const int p = kt >> 1, ks = kt & 1;
            #pragma unroll
            for (int mi = 0; mi < 4; ++mi) {
                const int off = ((mi * 16 + l15) << 9) + p * 128 + ks * 64 + lk * 16;
                af[mi] = *(const i32x4*)(R0 + (off ^ swz));
            }
            #pragma unroll
            for (int mi = 0; mi < 4; ++mi)
                #pragma unroll
                for (int ni = 0; ni < 4; ++ni)
                    mfma_bf16(acc[mi][ni], af[mi], ((kt & 1) ? bfQ : bfP)[ni]);
        }
    }

    // ===== LN1 + relu -> H1 bf16 [64][512B] swz (DPP reductions) =====
    float bb[4], gg[4], ee[4];
    #pragma unroll
    for (int ni = 0; ni < 4; ++ni) {
        const int c = wid * 64 + ni * 16 + l15;
        bb[ni] = b1[u * 256 + c]; gg[ni] = g1[u * 256 + c]; ee[ni] = be1[u * 256 + c];
    }
    #pragma unroll
    for (int mi = 0; mi < 4; ++mi) {
        #pragma unroll
        for (int j = 0; j < 4; ++j) {
            float s = 0.f, q = 0.f;
            #pragma unroll
            for (int ni = 0; ni < 4; ++ni) {
                const float h = acc[mi][ni][j] * corru + bb[ni];
                acc[mi][ni][j] = h;
                s += h; q += h * h;
            }
            s = red16(s); q = red16(q);
            if (l15 == 0) {
                const int r = mi * 16 + lk * 4 + j;
                pS[wid * 64 + r] = s; pQ[wid * 64 + r] = q;
            }
        }
    }
    __syncthreads();  // B1
    if (t < 64) {
        const float s = pS[t] + pS[64 + t] + pS[128 + t] + pS[192 + t];
        const float q = pQ[t] + pQ[64 + t] + pQ[128 + t] + pQ[192 + t];
        const float mean = s * (1.f / 256.f);
        const float var = fmaxf(q * (1.f / 256.f) - mean * mean, 0.f);
        rst[t] = make_float2(mean, rsqrtf(var + 1e-5f));
    }
    __syncthreads();  // B2
    #pragma unroll
    for (int mi = 0; mi < 4; ++mi) {
        #pragma unroll
        for (int j = 0; j < 4; ++j) {
            const int r = mi * 16 + lk * 4 + j;
            const float2 st = rst[r];
            #pragma unroll
            for (int ni = 0; ni < 4; ++ni) {
                const float h = fmaxf((acc[mi][ni][j] - st.x) * st.y * gg[ni] + ee[ni], 0.f);
                const int c = wid * 64 + ni * 16 + l15;
                const int off = (r << 9) + c * 2;
                *(__bf16*)(R0 + (off ^ ((r & 7) << 4))) = (__bf16)h;
            }
        }
    }
    __syncthreads();  // B3: H1 ready

    // ===== GEMM2: [64][128] = H1 @ W2t, K=256, reg double-buffer =====
    f32x4 acc2[4][2];
    #pragma unroll
    for (int mi = 0; mi < 4; ++mi) { acc2[mi][0] = z4; acc2[mi][1] = z4; }
    {
        i32x4 bfP[2], bfQ[2];
        #pragma unroll
        for (int ni = 0; ni < 2; ++ni)
            bfP[ni] = *(const i32x4*)(w2u + ((wid * 2 + ni) * 8 + 0) * 1024 + lo64);
        #pragma unroll
        for (int kt = 0; kt < 8; ++kt) {
            if (kt < 7) {
                #pragma unroll
                for (int ni = 0; ni < 2; ++ni)
                    ((kt & 1) ? bfP : bfQ)[ni] =
                        *(const i32x4*)(w2u + ((wid * 2 + ni) * 8 + kt + 1) * 1024 + lo64);
            }
            i32x4 af[4];
            const int p = kt >> 1, ks = kt & 1;
            #pragma unroll
            for (int mi = 0; mi < 4; ++mi) {
                const int off = ((mi * 16 + l15) << 9) + p * 128 + ks * 64 + lk * 16;
                af[mi] = *(const i32x4*)(R0 + (off ^ swz));
            }
            #pragma unroll
            for (int mi = 0; mi < 4; ++mi)
                #pragma unroll
                for (int ni = 0; ni < 2; ++ni)
                    mfma_bf16(acc2[mi][ni], af[mi], ((kt & 1) ? bfQ : bfP)[ni]);
        }
    }

    // ===== LN2 + relu -> H2 bf16 [64][256B] at [0,16K) (DPP reductions) =====
    float bb2[2], gg2[2], ee2[2];
    #pragma unroll
    for (int ni = 0; ni < 2; ++ni) {
        const int c = wid * 32 + ni * 16 + l15;
        bb2[ni] = b2[u * 128 + c]; gg2[ni] = g2[u * 128 + c]; ee2[ni] = be2[u * 128 + c];
    }
    #pragma unroll
    for (int mi = 0; mi < 4; ++mi) {
        #pragma unroll
        for (int j = 0; j < 4; ++j) {
            float s = 0.f, q = 0.f;
            #pragma unroll
            for (int ni = 0; ni < 2; ++ni) {
                const float h = acc2[mi][ni][j] + bb2[ni];
                acc2[mi][ni][j] = h;
                s += h; q += h * h;
            }
            s = red16(s); q = red16(q);
            if (l15 == 0) {
                const int r = mi * 16 + lk * 4 + j;
                pS[wid * 64 + r] = s; pQ[wid * 64 + r] = q;
            }
        }
    }
    __syncthreads();  // B4
    if (t < 64) {
        const float s = pS[t] + pS[64 + t] + pS[128 + t] + pS[192 + t];
        const float q = pQ[t] + pQ[64 + t] + pQ[128 + t] + pQ[192 + t];
        const float mean = s * (1.f / 128.f);
        const float var = fmaxf(q * (1.f / 128.f) - mean * mean, 0.f);
        rst[t] = make_float2(mean, rsqrtf(var + 1e-5f));
    }
    __syncthreads();  // B5
    #pragma unroll
    for (int mi = 0; mi < 4; ++mi) {
        #pragma unroll
        for (int j = 0; j < 4; ++j) {
            const int r = mi * 16 + lk * 4 + j;
            const float2 st = rst[r];
            #pragma unroll
            for (int ni = 0; ni < 2; ++ni) {
                const float h = fmaxf((acc2[mi][ni][j] - st.x) * st.y * gg2[ni] + ee2[ni], 0.f);
                const int c = wid * 32 + ni * 16 + l15;
                const int off = (r << 8) + c * 2;
                *(__bf16*)(R0 + (off ^ ((r & 7) << 4))) = (__bf16)h;
            }
        }
    }
    __syncthreads();  // B6: H2 ready

    // ===== GEMM3: enc [64][64] = H2 @ W3t, K=128 =====
    f32x4 acc3[4];
    #pragma unroll
    for (int mi = 0; mi < 4; ++mi) acc3[mi] = z4;
    #pragma unroll
    for (int ks = 0; ks < 4; ++ks) {
        const i32x4 bfr = *(const i32x4*)(w3u + (wid * 4 + ks) * 1024 + lo64);
        #pragma unroll
        for (int mi = 0; mi < 4; ++mi) {
            const int off = ((mi * 16 + l15) << 8) + ks * 64 + lk * 16;
            const i32x4 afm = *(const i32x4*)(R0 + (off ^ swz));
            mfma_bf16(acc3[mi], afm, bfr);
        }
    }
    // epilogue: +b3 (f32 encr regs), sumsq partials via DPP
    const int c16 = wid * 16 + l15;
    const float b3v = b3[u * 64 + c16];
    float encr[4][4];
    #pragma unroll
    for (int mi = 0; mi < 4; ++mi) {
        #pragma unroll
        for (int j = 0; j < 4; ++j) {
            const float e = acc3[mi][j] + b3v;
            encr[mi][j] = e;
            const float q = red16(e * e);
            if (l15 == 0) {
                const int r = mi * 16 + lk * 4 + j;
                pQ[wid * 64 + r] = q;
            }
        }
    }
    __syncthreads();  // B7: all GEMM3 H2-reads done, partials visible
    if (t < 64) {
        const float q = pQ[t] + pQ[64 + t] + pQ[128 + t] + pQ[192 + t];
        dmis[t] = tanhf(dmu * q);
    }
    // enc bf16 -> [0,8192)
    #pragma unroll
    for (int mi = 0; mi < 4; ++mi) {
        #pragma unroll
        for (int j = 0; j < 4; ++j) {
            const int r = mi * 16 + lk * 4 + j;
            const int off = (r << 7) + c16 * 2;
            *(__bf16*)(R0 + (off ^ ((r & 7) << 4))) = (__bf16)encr[mi][j];
        }
    }
    __syncthreads();  // B8: enc + dmis ready

    // coalesced enc global store from LDS: line-aligned 128B rows
    {
        const int c8 = t & 7;
        #pragma unroll
        for (int pass = 0; pass < 2; ++pass) {
            const int row = pass * 32 + (t >> 3);
            const int off = (row << 7) + c8 * 16;
            const uint4 v = *(const uint4*)(R0 + (off ^ ((row & 7) << 4)));
            *(uint4*)((char*)enc_bfg + (((size_t)(b0 + row) * 128 + u) << 7) + c8 * 16) = v;
        }
    }

    // ===== Wr: re [64][64] = enc_bf @ Wrt, K=64; z -> bf16 hi/lo planes =====
    f32x4 accR[4];
    #pragma unroll
    for (int mi = 0; mi < 4; ++mi) accR[mi] = z4;
    #pragma unroll
    for (int ks = 0; ks < 2; ++ks) {
        const i32x4 bfr = *(const i32x4*)(wru + (wid * 2 + ks) * 1024 + lo64);
        #pragma unroll
        for (int mi = 0; mi < 4; ++mi) {
            const int off = ((mi * 16 + l15) << 7) + ks * 64 + lk * 16;
            const i32x4 afm = *(const i32x4*)(R0 + (off ^ swz));
            mfma_bf16(accR[mi], afm, bfr);
        }
    }
    const float brv = br[u * 64 + c16];
    #pragma unroll
    for (int mi = 0; mi < 4; ++mi) {
        #pragma unroll
        for (int j = 0; j < 4; ++j) {
            const int r = mi * 16 + lk * 4 + j;
            const float zv = accR[mi][j] + brv + dmis[r] * encr[mi][j];
            const __bf16 zh = (__bf16)zv;
            const __bf16 zl = (__bf16)(zv - (float)zh);
            const int off = (r << 7) + c16 * 2;
            const int sw = (r & 7) << 4;
            *(__bf16*)(R0 + 8192 + (off ^ sw)) = zh;
            *(__bf16*)(R0 + 16384 + (off ^ sw)) = zl;
        }
    }
    __syncthreads();  // B9: z planes ready, enc reads done

    // ===== a1 = relu(z@Wa1 + ba1), split-bf16 MFMA (fp32-accurate) =====
    // wave w owns rows w*16..w*16+15, cols 0..31
    f32x4 accA[2] = {z4, z4};
    #pragma unroll
    for (int ks = 0; ks < 2; ++ks) {
        const int zoff = ((wid * 16 + l15) << 7) + ks * 64 + lk * 16;
        const int zsw = (l15 & 7) << 4;
        const i32x4 zh = *(const i32x4*)(R0 + 8192 + (zoff ^ zsw));
        const i32x4 zl = *(const i32x4*)(R0 + 16384 + (zoff ^ zsw));
        #pragma unroll
        for (int ni = 0; ni < 2; ++ni) {
            const i32x4 bh = *(const i32x4*)(wa1u + (ni * 2 + ks) * 1024 + lo64);
            const i32x4 bl = *(const i32x4*)(wa1u + 4096 + (ni * 2 + ks) * 1024 + lo64);
            mfma_bf16(accA[ni], zh, bh);
            mfma_bf16(accA[ni], zl, bh);
            mfma_bf16(accA[ni], zh, bl);
        }
    }
    // relu+bias, split a1 hi/lo -> LDS [64][64B] planes (same-wave RAW, no barrier)
    #pragma unroll
    for (int ni = 0; ni < 2; ++ni) {
        const float bav = ba1[u * 32 + ni * 16 + l15];
        #pragma unroll
        for (int j = 0; j < 4; ++j) {
            const int row = wid * 16 + lk * 4 + j;
            const float av = fmaxf(accA[ni][j] + bav, 0.f);
            const __bf16 ah = (__bf16)av;
            const __bf16 al = (__bf16)(av - (float)ah);
            const int off = (row << 6) + (ni * 16 + l15) * 2;
            const int sw = (row & 3) << 4;
            *(__bf16*)(R0 + 24576 + (off ^ sw)) = ah;
            *(__bf16*)(R0 + 28672 + (off ^ sw)) = al;
        }
    }

    // ===== a2 = relu(a1@Wa2 + ba2), split-bf16 MFMA; scores via DPP dot =====
    f32x4 accB = z4;
    {
        const int row = wid * 16 + l15;
        const int aoff = (row << 6) + lk * 16;
        const int asw = (l15 & 3) << 4;
        const i32x4 ah = *(const i32x4*)(R0 + 24576 + (aoff ^ asw));
        const i32x4 al = *(const i32x4*)(R0 + 28672 + (aoff ^ asw));
        const i32x4 bh = *(const i32x4*)(wa2u + lo64);
        const i32x4 bl = *(const i32x4*)(wa2u + 1024 + lo64);
        mfma_bf16(accB, ah, bh);
        mfma_bf16(accB, al, bh);
        mfma_bf16(accB, ah, bl);
    }
    const float ba2v = ba2[u * 16 + l15];
    const float wa3v = Wa3[u * 16 + l15];
    const float ba3u = ba3[u];
    #pragma unroll
    for (int j = 0; j < 4; ++j) {
        const float vsum = red16(fmaxf(accB[j] + ba2v, 0.f) * wa3v);
        if (l15 == 0) {
            const int r = wid * 16 + lk * 4 + j;
            scores_g[(size_t)u * 1024 + b0 + r] = 1.f / (1.f + __expf(-(vsum + ba3u)));
        }
    }
}

// ---------------- attention: MFMA proj + per-head MFMA S + DPP softmax ----------------
__global__ __launch_bounds__(256, 3)
void attn_kernel(const unsigned short* __restrict__ enc_bf,
                 const unsigned short* __restrict__ wqkv_bf,
                 const float* __restrict__ bqkv, float* __restrict__ smean,
                 float* __restrict__ bpart)
{
    __shared__ __align__(128) char sm[34944];
    char* Qp = sm;
    char* Ks = sm + 16384;
    float* colp = (float*)(sm + 32832);
    char* ENCs = sm;
    char* WQs  = sm + 16384;

    const int t = threadIdx.x;
    const int wid = t >> 6, lane = t & 63, l15 = lane & 15, lk = lane >> 4;
    const int swz = (l15 & 7) << 4;
    const int b = blockIdx.x;

    const char* eb = (const char*)(enc_bf + (size_t)b * 8192);
    #pragma unroll
    for (int it = 0; it < 4; ++it) {
        const int d = it * 4096 + t * 16;
        const int s = d ^ (((d >> 7) & 7) << 4);
        gl_lds16(eb + s, ENCs + it * 4096 + wid * 1024);
    }
    const char* wb = (const char*)wqkv_bf;
    #pragma unroll
    for (int it = 0; it < 4; ++it) {
        const int d = it * 4096 + t * 16;
        const int s = d ^ (((d >> 7) & 7) << 4);
        gl_lds16(wb + s, WQs + it * 4096 + wid * 1024);
    }
    __syncthreads();

    const f32x4 z4 = {0.f,0.f,0.f,0.f};
    f32x4 aq[2][4], ak[2][4];
    #pragma unroll
    for (int mi = 0; mi < 2; ++mi)
        #pragma unroll
        for (int ni = 0; ni < 4; ++ni) { aq[mi][ni] = z4; ak[mi][ni] = z4; }

    i32x4 af[2][2];
    #pragma unroll
    for (int mi = 0; mi < 2; ++mi)
        #pragma unroll
        for (int ks = 0; ks < 2; ++ks) {
            const int off = ((wid * 32 + mi * 16 + l15) << 7) + ks * 64 + lk * 16;
            af[mi][ks] = *(const i32x4*)(ENCs + (off ^ swz));
        }
    #pragma unroll
    for (int ni = 0; ni < 4; ++ni)
        #pragma unroll
        for (int ks = 0; ks < 2; ++ks) {
            const int offq = ((ni * 16 + l15) << 7) + ks * 64 + lk * 16;
            const i32x4 bq = *(const i32x4*)(WQs + (offq ^ swz));
            mfma_bf16(aq[0][ni], af[0][ks], bq);
            mfma_bf16(aq[1][ni], af[1][ks], bq);
            const i32x4 bk = *(const i32x4*)(WQs + ((offq + 8192) ^ swz));
            mfma_bf16(ak[0][ni], af[0][ks], bk);
            mfma_bf16(ak[1][ni], af[1][ks], bk);
        }

    float bqv[4], bkv[4];
    #pragma unroll
    for (int ni = 0; ni < 4; ++ni) {
        bqv[ni] = bqkv[ni * 16 + l15];
        bkv[ni] = bqkv[64 + ni * 16 + l15];
    }
    __syncthreads();

    {
        const int par = t >> 7, row = t & 127;
        char* base = Qp + par * 8192 + row * 64;
        *(f32x4*)(base + 16) = z4;
        *(f32x4*)(base + 32) = z4;
        *(f32x4*)(base + 48) = z4;
    }
    #pragma unroll
    for (int mi = 0; mi < 2; ++mi)
        #pragma unroll
        for (int ni = 0; ni < 4; ++ni)
            #pragma unroll
            for (int j = 0; j < 4; ++j) {
                const int row = wid * 32 + mi * 16 + lk * 4 + j;
                const int f = ni * 16 + l15;
                const int off = row * 128 + f * 2;
                *(__bf16*)(Ks + (off ^ ((row & 7) << 4))) = (__bf16)(ak[mi][ni][j] + bkv[ni]);
            }
    __syncthreads();

    const float qscale = 0.35355339059327373f;
    float cp[8] = {0.f,0.f,0.f,0.f,0.f,0.f,0.f,0.f};

    #pragma unroll
    for (int p = 0; p < 4; ++p) {
        #pragma unroll
        for (int mi = 0; mi < 2; ++mi)
            #pragma unroll
            for (int j = 0; j < 4; ++j) {
                const int row = wid * 32 + mi * 16 + lk * 4 + j;
                *(__bf16*)(Qp + (l15 >> 3) * 8192 + row * 64 + (l15 & 7) * 2) =
                    (__bf16)((aq[mi][p][j] + bqv[p]) * qscale);
            }
        __syncthreads();

        #pragma unroll 1
        for (int par = 0; par < 2; ++par) {
            const int h = p * 2 + par;
            const i32x4 aQ0 = *(const i32x4*)(Qp + par * 8192 + (wid * 32 + l15) * 64 + lk * 16);
            const i32x4 aQ1 = *(const i32x4*)(Qp + par * 8192 + (wid * 32 + 16 + l15) * 64 + lk * 16);
            f32x4 accS[2][8];
            #pragma unroll
            for (int ci = 0; ci < 8; ++ci) { accS[0][ci] = z4; accS[1][ci] = z4; }
            #pragma unroll
            for (int ci = 0; ci < 8; ++ci) {
                const int col = ci * 16 + l15;
                const i32x4 bK = *(const i32x4*)(Ks + ((col * 128 + ((h + lk) & 7) * 16) ^ ((col & 7) << 4)));
                mfma_bf16(accS[0][ci], aQ0, bK);
                mfma_bf16(accS[1][ci], aQ1, bK);
            }
            #pragma unroll
            for (int mi = 0; mi < 2; ++mi)
                #pragma unroll
                for (int j = 0; j < 4; ++j) {
                    float e[8];
                    float z = 0.f;
                    #pragma unroll
                    for (int ci = 0; ci < 8; ++ci) { e[ci] = __expf(accS[mi][ci][j]); z += e[ci]; }
                    z = red16(z);
                    const float zi = 1.f / z;
                    #pragma unroll
                    for (int ci = 0; ci < 8; ++ci) cp[ci] += e[ci] * zi;
                }
        }
        __syncthreads();
    }

    #pragma unroll
    for (int ci = 0; ci < 8; ++ci) {
        cp[ci] += __shfl_xor(cp[ci], 16);
        cp[ci] += __shfl_xor(cp[ci], 32);
    }
    if (lk == 0) {
        #pragma unroll
        for (int ci = 0; ci < 8; ++ci)
            colp[wid * 128 + ci * 16 + l15] = cp[ci];
    }
    __syncthreads();
    float v = 0.f;
    if (t < 128) {
        v = colp[t] + colp[128 + t] + colp[256 + t] + colp[384 + t];
        smean[(size_t)b * 128 + t] = v * (1.f / 1024.f);
    }
    #pragma unroll
    for (int m = 1; m < 64; m <<= 1) v += __shfl_xor(v, m);
    if (lane == 0) colp[512 + wid] = v;
    __syncthreads();
    if (t == 0)
        bpart[b] = (colp[512] + colp[513] + colp[514] + colp[515]) * (1.f / 1024.f);
}

__global__ __launch_bounds__(64)
void final_kernel(const float* __restrict__ scores_g, const float* __restrict__ smean,
                  const float* __restrict__ Wc1, const float* __restrict__ bc1,
                  const float* __restrict__ Wc2, const float* __restrict__ bc2,
                  const float* __restrict__ Wc3, const float* __restrict__ bc3,
                  float* __restrict__ out)
{
    __shared__ float sc[128];
    __shared__ float c1[64];
    __shared__ float c2[32];
    const int b = blockIdx.x, t = threadIdx.x;
    const float s0 = scores_g[(size_t)t * 1024 + b];
    const float s1 = scores_g[(size_t)(t + 64) * 1024 + b];
    sc[t] = s0; sc[64 + t] = s1;
    const float v0 = smean[(size_t)b * 128 + t];
    const float v1 = smean[(size_t)b * 128 + 64 + t];
    __syncthreads();
    float a = bc1[t];
    #pragma unroll 8
    for (int i = 0; i < 128; ++i) a += sc[i] * Wc1[i * 64 + t];
    c1[t] = fmaxf(a, 0.f);
    __syncthreads();
    if (t < 32) {
        float a2 = bc2[t];
        #pragma unroll 8
        for (int i = 0; i < 64; ++i) a2 += c1[i] * Wc2[i * 32 + t];
        c2[t] = fmaxf(a2, 0.f);
    }
    __syncthreads();
    float p = (t < 32) ? c2[t] * Wc3[t] : 0.f;
    #pragma unroll
    for (int m = 1; m < 64; m <<= 1) p += __shfl_xor(p, m);
    const float cons = 1.f / (1.f + __expf(-(p + bc3[0])));

    float sum = s0 + s1;
    float sq  = s0 * s0 + s1 * s1;
    float wsm = s0 * v0 + s1 * v1;
    float na  = (s0 > 0.1f ? 1.f : 0.f) + (s1 > 0.1f ? 1.f : 0.f);
    #pragma unroll
    for (int m = 1; m < 64; m <<= 1) {
        sum += __shfl_xor(sum, m); sq += __shfl_xor(sq, m);
        wsm += __shfl_xor(wsm, m); na += __shfl_xor(na, m);
    }
    if (t == 0) {
        const float mean = sum * (1.f / 128.f);
        float var = (sq - 128.f * mean * mean) * (1.f / 127.f);
        var = fmaxf(var, 0.f);
        const float agree = 1.f - sqrtf(var) / (mean + 1e-8f);
        out[b]        = cons * wsm;
        out[1024 + b] = (cons > 0.95f) ? 1.f : 0.f;
        out[2048 + b] = agree;
        out[3072 + b] = cons;
        out[4097 + b] = na;
    }
}

__global__ __launch_bounds__(256)
void attnmean_kernel(const float* __restrict__ bpart, float* __restrict__ out)
{
    __shared__ float red[4];
    const int t = threadIdx.x;
    const int lane = t & 63, wid = t >> 6;
    float s = bpart[t] + bpart[256 + t] + bpart[512 + t] + bpart[768 + t];
    #pragma unroll
    for (int m = 1; m < 64; m <<= 1) s += __shfl_xor(s, m);
    if (lane == 0) red[wid] = s;
    __syncthreads();
    if (t == 0) out[4096] = (red[0] + red[1] + red[2] + red[3]) * (1.f / 131072.f);
}

extern "C" void kernel_launch(void* const* d_in, const int* in_sizes, int n_in,
                              void* d_out, int out_size, void* d_ws, size_t ws_size,
                              hipStream_t stream)
{
    const float* x    = (const float*)d_in[0];
    const float* fs   = (const float*)d_in[1];
    const float* dm   = (const float*)d_in[2];
    const float* W1   = (const float*)d_in[3];
    const float* b1   = (const float*)d_in[4];
    const float* g1   = (const float*)d_in[5];
    const float* be1  = (const float*)d_in[6];
    const float* W2   = (const float*)d_in[7];
    const float* b2   = (const float*)d_in[8];
    const float* g2   = (const float*)d_in[9];
    const float* be2  = (const float*)d_in[10];
    const float* W3   = (const float*)d_in[11];
    const float* b3   = (const float*)d_in[12];
    const float* Wr   = (const float*)d_in[13];
    const float* br   = (const float*)d_in[14];
    const float* Wa1  = (const float*)d_in[15];
    const float* ba1  = (const float*)d_in[16];
    const float* Wa2  = (const float*)d_in[17];
    const float* ba2  = (const float*)d_in[18];
    const float* Wa3  = (const float*)d_in[19];
    const float* ba3  = (const float*)d_in[20];
    const float* Wqkv = (const float*)d_in[21];
    const float* bqkv = (const float*)d_in[22];
    // d_in[23]=Wo, d_in[24]=bo unused downstream
    const float* Wc1  = (const float*)d_in[25];
    const float* bc1  = (const float*)d_in[26];
    const float* Wc2  = (const float*)d_in[27];
    const float* bc2  = (const float*)d_in[28];
    const float* Wc3  = (const float*)d_in[29];
    const float* bc3  = (const float*)d_in[30];

    float* out = (float*)d_out;
    char*  ws8 = (char*)d_ws;
    unsigned short* enc_bf = (unsigned short*)ws8;             // 16 MB
    float* scores = (float*)(ws8 + 16777216);                  // 512 KB  [u][B]
    float* smean  = (float*)(ws8 + 17301504);                  // 512 KB
    float* bpart  = (float*)(ws8 + 17825792);                  // 4 KB
    unsigned short* xb    = (unsigned short*)(ws8 + 17829888); // 512 KB
    unsigned short* W1t   = (unsigned short*)(ws8 + 18354176); // 16 MB
    unsigned short* W2t   = (unsigned short*)(ws8 + 35131392); // 8 MB
    unsigned short* W3t   = (unsigned short*)(ws8 + 43520000); // 2 MB
    unsigned short* Wrt   = (unsigned short*)(ws8 + 45617152); // 1 MB
    unsigned short* wqkvb = (unsigned short*)(ws8 + 46665728); // 16 KB
    unsigned short* Wa1t  = (unsigned short*)(ws8 + 46682112); // 1 MB (hi+lo)
    unsigned short* Wa2t  = (unsigned short*)(ws8 + 47730688); // 256 KB (hi+lo)

    prep_kernel<<<3716, 256, 0, stream>>>(W1, W2, W3, Wr, Wa1, Wa2, x, Wqkv,
                                          W1t, W2t, W3t, Wrt, Wa1t, Wa2t, xb, wqkvb);
    fused_mfma<<<2048, 256, 0, stream>>>(xb, W1t, W2t, W3t, Wrt, Wa1t, Wa2t, fs, dm,
                                         b1, g1, be1, b2, g2, be2, b3, br,
                                         ba1, ba2, Wa3, ba3,
                                         enc_bf, scores);
    attn_kernel<<<1024, 256, 0, stream>>>(enc_bf, wqkvb, bqkv, smean, bpart);
    final_kernel<<<1024, 64, 0, stream>>>(scores, smean, Wc1, bc1, Wc2, bc2, Wc3, bc3, out);
    attnmean_kernel<<<1, 256, 0, stream>>>(bpart, out);
}

// Round 11
// 121.431 us; speedup vs baseline: 1.2272x; 1.0035x over previous
//
#include <hip/hip_runtime.h>
#include <math.h>

// U=128, D=256, B=1024, E=64, H=8
// prep_kernel : f32 -> bf16 frag-tiled weights [n/16][k/32][16][32] + x/wqkv -> bf16
//               + Wa1/Wa2 hi/lo bf16-split frag-tiled planes
// fused_mfma  : big GEMMs via MFMA with DIRECT global B-fragments; LN reductions
//               via DPP (VALU, no LDS); tail via split-bf16 MFMA (fp32-accurate).
// attn_kernel : MFMA Q/K proj + per-head MFMA S + DPP softmax + column sums
// final/attnmean: outputs

typedef float f32x4 __attribute__((ext_vector_type(4)));
typedef int   i32x4 __attribute__((ext_vector_type(4)));

__device__ __forceinline__ void mfma_bf16(f32x4& c, i32x4 a, i32x4 b) {
    asm("v_mfma_f32_16x16x32_bf16 %0, %1, %2, %0" : "+v"(c) : "v"(a), "v"(b));
}

__device__ __forceinline__ void gl_lds16(const void* g, void* l) {
    __builtin_amdgcn_global_load_lds(
        (const __attribute__((address_space(1))) unsigned int*)g,
        (__attribute__((address_space(3))) unsigned int*)l, 16, 0, 0);
}

__device__ __forceinline__ unsigned short f2bf(float v) {
    union { __bf16 b; unsigned short u; } cv;
    cv.b = (__bf16)v;
    return cv.u;
}
__device__ __forceinline__ float bf2f(unsigned short u) {
    union { unsigned int i; float f; } c; c.i = (unsigned int)u << 16; return c.f;
}

// sum over each 16-lane group via DPP (pure VALU, no LDS pipe):
// xor1 (quad_perm 1,0,3,2) + xor2 (quad_perm 2,3,0,1) + row_ror:4 + row_ror:8
__device__ __forceinline__ float red16(float v) {
    int x;
    x = __builtin_amdgcn_update_dpp(0, __float_as_int(v), 0xB1, 0xF, 0xF, true);
    v += __int_as_float(x);
    x = __builtin_amdgcn_update_dpp(0, __float_as_int(v), 0x4E, 0xF, 0xF, true);
    v += __int_as_float(x);
    x = __builtin_amdgcn_update_dpp(0, __float_as_int(v), 0x124, 0xF, 0xF, true);
    v += __int_as_float(x);
    x = __builtin_amdgcn_update_dpp(0, __float_as_int(v), 0x128, 0xF, 0xF, true);
    v += __int_as_float(x);
    return v;
}

// ---------------- prep: convert + frag-tile weights to bf16 ----------------
__global__ __launch_bounds__(256)
void prep_kernel(const float* __restrict__ W1, const float* __restrict__ W2,
                 const float* __restrict__ W3, const float* __restrict__ Wr,
                 const float* __restrict__ Wa1, const float* __restrict__ Wa2,
                 const float* __restrict__ x, const float* __restrict__ Wqkv,
                 unsigned short* __restrict__ W1t, unsigned short* __restrict__ W2t,
                 unsigned short* __restrict__ W3t, unsigned short* __restrict__ Wrt,
                 unsigned short* __restrict__ Wa1t, unsigned short* __restrict__ Wa2t,
                 unsigned short* __restrict__ xb, unsigned short* __restrict__ wqkvb)
{
    const int bid = blockIdx.x, t = threadIdx.x;
    if (bid >= 3588) {  // Wa1/Wa2 hi/lo split + frag-tile, one u per block
        const int uu = bid - 3588;
        #pragma unroll
        for (int i = 0; i < 8; ++i) {
            const int e = t * 8 + i;            // 0..2047
            const int k = e >> 5, n = e & 31;   // Wa1 [64 k][32 n]
            const float v = Wa1[(size_t)uu * 2048 + k * 32 + n];
            const unsigned short h = f2bf(v);
            const unsigned short l = f2bf(v - bf2f(h));
            const size_t d = (size_t)uu * 4096 +
                (((n >> 4) * 2 + (k >> 5)) * 512 + (n & 15) * 32 + (k & 31));
            Wa1t[d] = h; Wa1t[d + 2048] = l;
        }
        #pragma unroll
        for (int i = 0; i < 2; ++i) {
            const int e = t * 2 + i;            // 0..511
            const int k = e >> 4, n = e & 15;   // Wa2 [32 k][16 n]
            const float v = Wa2[(size_t)uu * 512 + k * 16 + n];
            const unsigned short h = f2bf(v);
            const unsigned short l = f2bf(v - bf2f(h));
            const size_t d = (size_t)uu * 1024 + n * 32 + k;
            Wa2t[d] = h; Wa2t[d + 512] = l;
        }
        return;
    }
    if (bid >= 3456) {  // plain convert, no transpose
        const float* src; unsigned short* dst; int base;
        if (bid >= 3584) { src = Wqkv; dst = wqkvb; base = (bid - 3584) * 2048 + t * 8; }
        else             { src = x;    dst = xb;    base = (bid - 3456) * 2048 + t * 8; }
        const float4 v0 = *(const float4*)(src + base);
        const float4 v1 = *(const float4*)(src + base + 4);
        __align__(16) unsigned short o[8];
        o[0]=f2bf(v0.x); o[1]=f2bf(v0.y); o[2]=f2bf(v0.z); o[3]=f2bf(v0.w);
        o[4]=f2bf(v1.x); o[5]=f2bf(v1.y); o[6]=f2bf(v1.z); o[7]=f2bf(v1.w);
        *(uint4*)(dst + base) = *(const uint4*)o;
        return;
    }
    const float* src; unsigned short* dst; int u, k0, n0, N, ktiles;
    if (bid < 2048)      { u = bid >> 4;        int tl = bid & 15;       k0 = (tl>>2)*64; n0 = (tl&3)*64; N=256; ktiles=8; src = W1 + (size_t)u*65536; dst = W1t + (size_t)u*65536; }
    else if (bid < 3072) { int b2 = bid - 2048; u = b2 >> 3; int tl = b2 & 7; k0 = (tl>>1)*64; n0 = (tl&1)*64; N=128; ktiles=8; src = W2 + (size_t)u*32768; dst = W2t + (size_t)u*32768; }
    else if (bid < 3328) { int b3 = bid - 3072; u = b3 >> 1; int tl = b3 & 1; k0 = tl*64;      n0 = 0;         N=64;  ktiles=4; src = W3 + (size_t)u*8192;  dst = W3t + (size_t)u*8192;  }
    else                 { u = bid - 3328;      k0 = 0; n0 = 0;                                 N=64;  ktiles=2; src = Wr + (size_t)u*4096;  dst = Wrt + (size_t)u*4096;  }

    __shared__ unsigned short tile[64 * 65];
    #pragma unroll
    for (int i = 0; i < 16; ++i) {
        const int e = i * 256 + t;
        const int kk = e >> 6, nn = e & 63;
        tile[kk * 65 + nn] = f2bf(src[(size_t)(k0 + kk) * N + n0 + nn]);
    }
    __syncthreads();
    #pragma unroll
    for (int i = 0; i < 16; ++i) {
        const int e = i * 256 + t;
        const int nn = e >> 6, kk = e & 63;
        const int n = n0 + nn, k = k0 + kk;
        dst[(size_t)(((n >> 4) * ktiles + (k >> 5)) * 512 + (n & 15) * 32 + (k & 31))] = tile[kk * 65 + nn];
    }
}

// ---------------- fused universe chain ----------------
__global__ __launch_bounds__(256, 4)
void fused_mfma(const unsigned short* __restrict__ xb,
                const unsigned short* __restrict__ W1t, const unsigned short* __restrict__ W2t,
                const unsigned short* __restrict__ W3t, const unsigned short* __restrict__ Wrt,
                const unsigned short* __restrict__ Wa1t, const unsigned short* __restrict__ Wa2t,
                const float* __restrict__ fs, const float* __restrict__ dm,
                const float* __restrict__ b1, const float* __restrict__ g1, const float* __restrict__ be1,
                const float* __restrict__ b2, const float* __restrict__ g2, const float* __restrict__ be2,
                const float* __restrict__ b3, const float* __restrict__ br,
                const float* __restrict__ ba1, const float* __restrict__ ba2,
                const float* __restrict__ Wa3, const float* __restrict__ ba3,
                unsigned short* __restrict__ enc_bfg, float* __restrict__ scores_g)
{
    // LDS: [0,32768) A_x/H1 -> H2 [0,16K) -> enc [0,8K) ; z_hi [8192,16384),
    // z_lo [16384,24576) ; a1_hi [24576,28672), a1_lo [28672,32768) ;
    // stats at [36864,39680)
    __shared__ __align__(128) char sm[39680];
    char* R0 = sm;
    float* pS = (float*)(sm + 36864);
    float* pQ = (float*)(sm + 37888);
    float2* rst = (float2*)(sm + 38912);
    float* dmis = (float*)(sm + 39424);

    const int t = threadIdx.x;
    const int wid = t >> 6, lane = t & 63, l15 = lane & 15, lk = lane >> 4;
    const int swz = (l15 & 7) << 4;
    const int lo64 = l15 * 64 + lk * 16;
    const int bx = blockIdx.x;
    const int xcd = bx & 7, idx = bx >> 3;
    const int u = ((idx >> 4) << 3) + xcd;
    const int b0 = (idx & 15) * 64;

    const float corru = fs[u] * 137.036f;
    const float dmu = dm[u];

    const char* xbase = (const char*)xb + (size_t)b0 * 512;
    const char* w1u = (const char*)W1t + (size_t)u * 131072;
    const char* w2u = (const char*)W2t + (size_t)u * 65536;
    const char* w3u = (const char*)W3t + (size_t)u * 16384;
    const char* wru = (const char*)Wrt + (size_t)u * 8192;
    const char* wa1u = (const char*)Wa1t + (size_t)u * 8192;
    const char* wa2u = (const char*)Wa2t + (size_t)u * 2048;

    #pragma unroll
    for (int it = 0; it < 8; ++it) {
        const int d = it * 4096 + t * 16;
        const int s = d ^ (((d >> 9) & 7) << 4);
        gl_lds16(xbase + s, R0 + it * 4096 + wid * 1024);
    }
    __syncthreads();  // B0

    // ===== GEMM1: [64][256] = A_x @ W1t, K=256, B direct + reg double-buffer =====
    const f32x4 z4 = {0.f, 0.f, 0.f, 0.f};
    f32x4 acc[4][4];
    #pragma unroll
    for (int mi = 0; mi < 4; ++mi)
        #pragma unroll
        for (int ni = 0; ni < 4; ++ni) acc[mi][ni] = z4;

    {
        i32x4 bfP[4], bfQ[4];
        #pragma unroll
        for (int ni = 0; ni < 4; ++ni)
            bfP[ni] = *(const i32x4*)(w1u + ((wid * 4 + ni) * 8 + 0) * 1024 + lo64);
        #pragma unroll
        for (int kt = 0; kt < 8; ++kt) {
            if (kt < 7) {
                #pragma unroll
                for (int ni = 0; ni < 4; ++ni)
                    ((kt & 1) ? bfP : bfQ)[ni] =
                        *(const i32x4*)(w1u + ((wid * 4 + ni) * 8 + kt + 1) * 1024 + lo64);
            }
            i32x4 af[4];
            const int p = kt >> 1, ks = kt & 1;
            #pragma unroll
            for (int mi = 0; mi < 4; ++mi) {
                const int off = ((mi * 16 + l15) << 9) + p * 128 + ks * 64 + lk * 16;
                af[mi] = *(const i32x4*)(R0 + (off ^ swz));
            }
            #pragma unroll
            for (int mi = 0; mi < 4; ++mi)
                #pragma unroll
                for (int ni = 0; ni < 4; ++ni)
                    mfma_bf16(acc[mi][ni], af[mi], ((kt & 1) ? bfQ : bfP)[ni]);
        }
    }

    // ===== LN1 + relu -> H1 bf16 [64][512B] swz (DPP reductions) =====
    float bb[4], gg[4], ee[4];
    #pragma unroll
    for (int ni = 0; ni < 4; ++ni) {
        const int c = wid * 64 + ni * 16 + l15;
        bb[ni] = b1[u * 256 + c]; gg[ni] = g1[u * 256 + c]; ee[ni] = be1[u * 256 + c];
    }
    #pragma unroll
    for (int mi = 0; mi < 4; ++mi) {
        #pragma unroll
        for (int j = 0; j < 4; ++j) {
            float s = 0.f, q = 0.f;
            #pragma unroll
            for (int ni = 0; ni < 4; ++ni) {
                const float h = acc[mi][ni][j] * corru + bb[ni];
                acc[mi][ni][j] = h;
                s += h; q += h * h;
            }
            s = red16(s); q = red16(q);
            if (l15 == 0) {
                const int r = mi * 16 + lk * 4 + j;
                pS[wid * 64 + r] = s; pQ[wid * 64 + r] = q;
            }
        }
    }
    __syncthreads();  // B1
    if (t < 64) {
        const float s = pS[t] + pS[64 + t] + pS[128 + t] + pS[192 + t];
        const float q = pQ[t] + pQ[64 + t] + pQ[128 + t] + pQ[192 + t];
        const float mean = s * (1.f / 256.f);
        const float var = fmaxf(q * (1.f / 256.f) - mean * mean, 0.f);
        rst[t] = make_float2(mean, rsqrtf(var + 1e-5f));
    }
    __syncthreads();  // B2
    #pragma unroll
    for (int mi = 0; mi < 4; ++mi) {
        #pragma unroll
        for (int j = 0; j < 4; ++j) {
            const int r = mi * 16 + lk * 4 + j;
            const float2 st = rst[r];
            #pragma unroll
            for (int ni = 0; ni < 4; ++ni) {
                const float h = fmaxf((acc[mi][ni][j] - st.x) * st.y * gg[ni] + ee[ni], 0.f);
                const int c = wid * 64 + ni * 16 + l15;
                const int off = (r << 9) + c * 2;
                *(__bf16*)(R0 + (off ^ ((r & 7) << 4))) = (__bf16)h;
            }
        }
    }
    __syncthreads();  // B3: H1 ready

    // ===== GEMM2: [64][128] = H1 @ W2t, K=256, reg double-buffer =====
    f32x4 acc2[4][2];
    #pragma unroll
    for (int mi = 0; mi < 4; ++mi) { acc2[mi][0] = z4; acc2[mi][1] = z4; }
    {
        i32x4 bfP[2], bfQ[2];
        #pragma unroll
        for (int ni = 0; ni < 2; ++ni)
            bfP[ni] = *(const i32x4*)(w2u + ((wid * 2 + ni) * 8 + 0) * 1024 + lo64);
        #pragma unroll
        for (int kt = 0; kt < 8; ++kt) {
            if (kt < 7) {
                #pragma unroll
                for (int ni = 0; ni < 2; ++ni)
                    ((kt & 1) ? bfP : bfQ)[ni] =
                        *(const i32x4*)(w2u + ((wid * 2 + ni) * 8 + kt + 1) * 1024 + lo64);
            }
            i32x4 af[4];
            const int p = kt >> 1, ks = kt & 1;
            #pragma unroll
            for (int mi = 0; mi < 4; ++mi) {
                const int off = ((mi * 16 + l15) << 9) + p * 128 + ks * 64 + lk * 16;
                af[mi] = *(const i32x4*)(R0 + (off ^ swz));
            }
            #pragma unroll
            for (int mi = 0; mi < 4; ++mi)
                #pragma unroll
                for (int ni = 0; ni < 2; ++ni)
                    mfma_bf16(acc2[mi][ni], af[mi], ((kt & 1) ? bfQ : bfP)[ni]);
        }
    }

    // ===== LN2 + relu -> H2 bf16 [64][256B] at [0,16K) (DPP reductions) =====
    float bb2[2], gg2[2], ee2[2];
    #pragma unroll
    for (int ni = 0; ni < 2; ++ni) {
        const int c = wid * 32 + ni * 16 + l15;
        bb2[ni] = b2[u * 128 + c]; gg2[ni] = g2[u * 128 + c]; ee2[ni] = be2[u * 128 + c];
    }
    #pragma unroll
    for (int mi = 0; mi < 4; ++mi) {
        #pragma unroll
        for (int j = 0; j < 4; ++j) {
            float s = 0.f, q = 0.f;
            #pragma unroll
            for (int ni = 0; ni < 2; ++ni) {
                const float h = acc2[mi][ni][j] + bb2[ni];
                acc2[mi][ni][j] = h;
                s += h; q += h * h;
            }
            s = red16(s); q = red16(q);
            if (l15 == 0) {
                const int r = mi * 16 + lk * 4 + j;
                pS[wid * 64 + r] = s; pQ[wid * 64 + r] = q;
            }
        }
    }
    __syncthreads();  // B4
    if (t < 64) {
        const float s = pS[t] + pS[64 + t] + pS[128 + t] + pS[192 + t];
        const float q = pQ[t] + pQ[64 + t] + pQ[128 + t] + pQ[192 + t];
        const float mean = s * (1.f / 128.f);
        const float var = fmaxf(q * (1.f / 128.f) - mean * mean, 0.f);
        rst[t] = make_float2(mean, rsqrtf(var + 1e-5f));
    }
    __syncthreads();  // B5
    #pragma unroll
    for (int mi = 0; mi < 4; ++mi) {
        #pragma unroll
        for (int j = 0; j < 4; ++j) {
            const int r = mi * 16 + lk * 4 + j;
            const float2 st = rst[r];
            #pragma unroll
            for (int ni = 0; ni < 2; ++ni) {
                const float h = fmaxf((acc2[mi][ni][j] - st.x) * st.y * gg2[ni] + ee2[ni], 0.f);
                const int c = wid * 32 + ni * 16 + l15;
                const int off = (r << 8) + c * 2;
                *(__bf16*)(R0 + (off ^ ((r & 7) << 4))) = (__bf16)h;
            }
        }
    }
    __syncthreads();  // B6: H2 ready

    // ===== GEMM3: enc [64][64] = H2 @ W3t, K=128 =====
    f32x4 acc3[4];
    #pragma unroll
    for (int mi = 0; mi < 4; ++mi) acc3[mi] = z4;
    #pragma unroll
    for (int ks = 0; ks < 4; ++ks) {
        const i32x4 bfr = *(const i32x4*)(w3u + (wid * 4 + ks) * 1024 + lo64);
        #pragma unroll
        for (int mi = 0; mi < 4; ++mi) {
            const int off = ((mi * 16 + l15) << 8) + ks * 64 + lk * 16;
            const i32x4 afm = *(const i32x4*)(R0 + (off ^ swz));
            mfma_bf16(acc3[mi], afm, bfr);
        }
    }
    // epilogue: +b3 (f32 encr regs), sumsq partials via DPP
    const int c16 = wid * 16 + l15;
    const float b3v = b3[u * 64 + c16];
    float encr[4][4];
    #pragma unroll
    for (int mi = 0; mi < 4; ++mi) {
        #pragma unroll
        for (int j = 0; j < 4; ++j) {
            const float e = acc3[mi][j] + b3v;
            encr[mi][j] = e;
            const float q = red16(e * e);
            if (l15 == 0) {
                const int r = mi * 16 + lk * 4 + j;
                pQ[wid * 64 + r] = q;
            }
        }
    }
    __syncthreads();  // B7: all GEMM3 H2-reads done, partials visible
    if (t < 64) {
        const float q = pQ[t] + pQ[64 + t] + pQ[128 + t] + pQ[192 + t];
        dmis[t] = tanhf(dmu * q);
    }
    // enc bf16 -> [0,8192)
    #pragma unroll
    for (int mi = 0; mi < 4; ++mi) {
        #pragma unroll
        for (int j = 0; j < 4; ++j) {
            const int r = mi * 16 + lk * 4 + j;
            const int off = (r << 7) + c16 * 2;
            *(__bf16*)(R0 + (off ^ ((r & 7) << 4))) = (__bf16)encr[mi][j];
        }
    }
    __syncthreads();  // B8: enc + dmis ready

    // coalesced enc global store from LDS: line-aligned 128B rows
    {
        const int c8 = t & 7;
        #pragma unroll
        for (int pass = 0; pass < 2; ++pass) {
            const int row = pass * 32 + (t >> 3);
            const int off = (row << 7) + c8 * 16;
            const uint4 v = *(const uint4*)(R0 + (off ^ ((row & 7) << 4)));
            *(uint4*)((char*)enc_bfg + (((size_t)(b0 + row) * 128 + u) << 7) + c8 * 16) = v;
        }
    }

    // ===== Wr: re [64][64] = enc_bf @ Wrt, K=64; z -> bf16 hi/lo planes =====
    f32x4 accR[4];
    #pragma unroll
    for (int mi = 0; mi < 4; ++mi) accR[mi] = z4;
    #pragma unroll
    for (int ks = 0; ks < 2; ++ks) {
        const i32x4 bfr = *(const i32x4*)(wru + (wid * 2 + ks) * 1024 + lo64);
        #pragma unroll
        for (int mi = 0; mi < 4; ++mi) {
            const int off = ((mi * 16 + l15) << 7) + ks * 64 + lk * 16;
            const i32x4 afm = *(const i32x4*)(R0 + (off ^ swz));
            mfma_bf16(accR[mi], afm, bfr);
        }
    }
    const float brv = br[u * 64 + c16];
    #pragma unroll
    for (int mi = 0; mi < 4; ++mi) {
        #pragma unroll
        for (int j = 0; j < 4; ++j) {
            const int r = mi * 16 + lk * 4 + j;
            const float zv = accR[mi][j] + brv + dmis[r] * encr[mi][j];
            const __bf16 zh = (__bf16)zv;
            const __bf16 zl = (__bf16)(zv - (float)zh);
            const int off = (r << 7) + c16 * 2;
            const int sw = (r & 7) << 4;
            *(__bf16*)(R0 + 8192 + (off ^ sw)) = zh;
            *(__bf16*)(R0 + 16384 + (off ^ sw)) = zl;
        }
    }
    __syncthreads();  // B9: z planes ready, enc reads done

    // ===== a1 = relu(z@Wa1 + ba1), split-bf16 MFMA (fp32-accurate) =====
    // wave w owns rows w*16..w*16+15, cols 0..31
    f32x4 accA[2] = {z4, z4};
    #pragma unroll
    for (int ks = 0; ks < 2; ++ks) {
        const int zoff = ((wid * 16 + l15) << 7) + ks * 64 + lk * 16;
        const int zsw = (l15 & 7) << 4;
        const i32x4 zh = *(const i32x4*)(R0 + 8192 + (zoff ^ zsw));
        const i32x4 zl = *(const i32x4*)(R0 + 16384 + (zoff ^ zsw));
        #pragma unroll
        for (int ni = 0; ni < 2; ++ni) {
            const i32x4 bh = *(const i32x4*)(wa1u + (ni * 2 + ks) * 1024 + lo64);
            const i32x4 bl = *(const i32x4*)(wa1u + 4096 + (ni * 2 + ks) * 1024 + lo64);
            mfma_bf16(accA[ni], zh, bh);
            mfma_bf16(accA[ni], zl, bh);
            mfma_bf16(accA[ni], zh, bl);
        }
    }
    // relu+bias, split a1 hi/lo -> LDS [64][64B] planes (same-wave RAW, no barrier)
    #pragma unroll
    for (int ni = 0; ni < 2; ++ni) {
        const float bav = ba1[u * 32 + ni * 16 + l15];
        #pragma unroll
        for (int j = 0; j < 4; ++j) {
            const int row = wid * 16 + lk * 4 + j;
            const float av = fmaxf(accA[ni][j] + bav, 0.f);
            const __bf16 ah = (__bf16)av;
            const __bf16 al = (__bf16)(av - (float)ah);
            const int off = (row << 6) + (ni * 16 + l15) * 2;
            const int sw = (row & 3) << 4;
            *(__bf16*)(R0 + 24576 + (off ^ sw)) = ah;
            *(__bf16*)(R0 + 28672 + (off ^ sw)) = al;
        }
    }

    // ===== a2 = relu(a1@Wa2 + ba2), split-bf16 MFMA; scores via DPP dot =====
    f32x4 accB = z4;
    {
        const int row = wid * 16 + l15;
        const int aoff = (row << 6) + lk * 16;
        const int asw = (l15 & 3) << 4;
        const i32x4 ah = *(const i32x4*)(R0 + 24576 + (aoff ^ asw));
        const i32x4 al = *(const i32x4*)(R0 + 28672 + (aoff ^ asw));
        const i32x4 bh = *(const i32x4*)(wa2u + lo64);
        const i32x4 bl = *(const i32x4*)(wa2u + 1024 + lo64);
        mfma_bf16(accB, ah, bh);
        mfma_bf16(accB, al, bh);
        mfma_bf16(accB, ah, bl);
    }
    const float ba2v = ba2[u * 16 + l15];
    const float wa3v = Wa3[u * 16 + l15];
    const float ba3u = ba3[u];
    #pragma unroll
    for (int j = 0; j < 4; ++j) {
        const float vsum = red16(fmaxf(accB[j] + ba2v, 0.f) * wa3v);
        if (l15 == 0) {
            const int r = wid * 16 + lk * 4 + j;
            scores_g[(size_t)u * 1024 + b0 + r] = 1.f / (1.f + __expf(-(vsum + ba3u)));
        }
    }
}

// ---------------- attention: MFMA proj + per-head MFMA S + DPP softmax ----------------
__global__ __launch_bounds__(256, 3)
void attn_kernel(const unsigned short* __restrict__ enc_bf,
                 const unsigned short* __restrict__ wqkv_bf,
                 const float* __restrict__ bqkv, float* __restrict__ smean,
                 float* __restrict__ bpart)
{
    __shared__ __align__(128) char sm[34944];
    char* Qp = sm;
    char* Ks = sm + 16384;
    float* colp = (float*)(sm + 32832);
    char* ENCs = sm;
    char* WQs  = sm + 16384;

    const int t = threadIdx.x;
    const int wid = t >> 6, lane = t & 63, l15 = lane & 15, lk = lane >> 4;
    const int swz = (l15 & 7) << 4;
    const int b = blockIdx.x;

    const char* eb = (const char*)(enc_bf + (size_t)b * 8192);
    #pragma unroll
    for (int it = 0; it < 4; ++it) {
        const int d = it * 4096 + t * 16;
        const int s = d ^ (((d >> 7) & 7) << 4);
        gl_lds16(eb + s, ENCs + it * 4096 + wid * 1024);
    }
    const char* wb = (const char*)wqkv_bf;
    #pragma unroll
    for (int it = 0; it < 4; ++it) {
        const int d = it * 4096 + t * 16;
        const int s = d ^ (((d >> 7) & 7) << 4);
        gl_lds16(wb + s, WQs + it * 4096 + wid * 1024);
    }
    __syncthreads();

    const f32x4 z4 = {0.f,0.f,0.f,0.f};
    f32x4 aq[2][4], ak[2][4];
    #pragma unroll
    for (int mi = 0; mi < 2; ++mi)
        #pragma unroll
        for (int ni = 0; ni < 4; ++ni) { aq[mi][ni] = z4; ak[mi][ni] = z4; }

    i32x4 af[2][2];
    #pragma unroll
    for (int mi = 0; mi < 2; ++mi)
        #pragma unroll
        for (int ks = 0; ks < 2; ++ks) {
            const int off = ((wid * 32 + mi * 16 + l15) << 7) + ks * 64 + lk * 16;
            af[mi][ks] = *(const i32x4*)(ENCs + (off ^ swz));
        }
    #pragma unroll
    for (int ni = 0; ni < 4; ++ni)
        #pragma unroll
        for (int ks = 0; ks < 2; ++ks) {
            const int offq = ((ni * 16 + l15) << 7) + ks * 64 + lk * 16;
            const i32x4 bq = *(const i32x4*)(WQs + (offq ^ swz));
            mfma_bf16(aq[0][ni], af[0][ks], bq);
            mfma_bf16(aq[1][ni], af[1][ks], bq);
            const i32x4 bk = *(const i32x4*)(WQs + ((offq + 8192) ^ swz));
            mfma_bf16(ak[0][ni], af[0][ks], bk);
            mfma_bf16(ak[1][ni], af[1][ks], bk);
        }

    float bqv[4], bkv[4];
    #pragma unroll
    for (int ni = 0; ni < 4; ++ni) {
        bqv[ni] = bqkv[ni * 16 + l15];
        bkv[ni] = bqkv[64 + ni * 16 + l15];
    }
    __syncthreads();

    {
        const int par = t >> 7, row = t & 127;
        char* base = Qp + par * 8192 + row * 64;
        *(f32x4*)(base + 16) = z4;
        *(f32x4*)(base + 32) = z4;
        *(f32x4*)(base + 48) = z4;
    }
    #pragma unroll
    for (int mi = 0; mi < 2; ++mi)
        #pragma unroll
        for (int ni = 0; ni < 4; ++ni)
            #pragma unroll
            for (int j = 0; j < 4; ++j) {
                const int row = wid * 32 + mi * 16 + lk * 4 + j;
                const int f = ni * 16 + l15;
                const int off = row * 128 + f * 2;
                *(__bf16*)(Ks + (off ^ ((row & 7) << 4))) = (__bf16)(ak[mi][ni][j] + bkv[ni]);
            }
    __syncthreads();

    const float qscale = 0.35355339059327373f;
    float cp[8] = {0.f,0.f,0.f,0.f,0.f,0.f,0.f,0.f};

    #pragma unroll
    for (int p = 0; p < 4; ++p) {
        #pragma unroll
        for (int mi = 0; mi < 2; ++mi)
            #pragma unroll
            for (int j = 0; j < 4; ++j) {
                const int row = wid * 32 + mi * 16 + lk * 4 + j;
                *(__bf16*)(Qp + (l15 >> 3) * 8192 + row * 64 + (l15 & 7) * 2) =
                    (__bf16)((aq[mi][p][j] + bqv[p]) * qscale);
            }
        __syncthreads();

        #pragma unroll 1
        for (int par = 0; par < 2; ++par) {
            const int h = p * 2 + par;
            const i32x4 aQ0 = *(const i32x4*)(Qp + par * 8192 + (wid * 32 + l15) * 64 + lk * 16);
            const i32x4 aQ1 = *(const i32x4*)(Qp + par * 8192 + (wid * 32 + 16 + l15) * 64 + lk * 16);
            f32x4 accS[2][8];
            #pragma unroll
            for (int ci = 0; ci < 8; ++ci) { accS[0][ci] = z4; accS[1][ci] = z4; }
            #pragma unroll
            for (int ci = 0; ci < 8; ++ci) {
                const int col = ci * 16 + l15;
                const i32x4 bK = *(const i32x4*)(Ks + ((col * 128 + ((h + lk) & 7) * 16) ^ ((col & 7) << 4)));
                mfma_bf16(accS[0][ci], aQ0, bK);
                mfma_bf16(accS[1][ci], aQ1, bK);
            }
            #pragma unroll
            for (int mi = 0; mi < 2; ++mi)
                #pragma unroll
                for (int j = 0; j < 4; ++j) {
                    float e[8];
                    float z = 0.f;
                    #pragma unroll
                    for (int ci = 0; ci < 8; ++ci) { e[ci] = __expf(accS[mi][ci][j]); z += e[ci]; }
                    z = red16(z);
                    const float zi = 1.f / z;
                    #pragma unroll
                    for (int ci = 0; ci < 8; ++ci) cp[ci] += e[ci] * zi;
                }
        }
        __syncthreads();
    }

    #pragma unroll
    for (int ci = 0; ci < 8; ++ci) {
        cp[ci] += __shfl_xor(cp[ci], 16);
        cp[ci] += __shfl_xor(cp[ci], 32);
    }
    if (lk == 0) {
        #pragma unroll
        for (int ci = 0; ci < 8; ++ci)
            colp[wid * 128 + ci * 16 + l15] = cp[ci];
    }
    __syncthreads();
    float v = 0.f;
    if (t < 128) {
        v = colp[t] + colp[128 + t] + colp[256 + t] + colp[384 + t];
        smean[(size_t)b * 128 + t] = v * (1.f / 1024.f);
    }
    #pragma unroll
    for (int m = 1; m < 64; m <<= 1) v += __shfl_xor(v, m);
    if (lane == 0) colp[512 + wid] = v;
    __syncthreads();
    if (t == 0)
        bpart[b] = (colp[512] + colp[513] + colp[514] + colp[515]) * (1.f / 1024.f);
}

__global__ __launch_bounds__(64)
void final_kernel(const float* __restrict__ scores_g, const float* __restrict__ smean,
                  const float* __restrict__ Wc1, const float* __restrict__ bc1,
                  const float* __restrict__ Wc2, const float* __restrict__ bc2,
                  const float* __restrict__ Wc3, const float* __restrict__ bc3,
                  float* __restrict__ out)
{
    __shared__ float sc[128];
    __shared__ float c1[64];
    __shared__ float c2[32];
    const int b = blockIdx.x, t = threadIdx.x;
    const float s0 = scores_g[(size_t)t * 1024 + b];
    const float s1 = scores_g[(size_t)(t + 64) * 1024 + b];
    sc[t] = s0; sc[64 + t] = s1;
    const float v0 = smean[(size_t)b * 128 + t];
    const float v1 = smean[(size_t)b * 128 + 64 + t];
    __syncthreads();
    float a = bc1[t];
    #pragma unroll 8
    for (int i = 0; i < 128; ++i) a += sc[i] * Wc1[i * 64 + t];
    c1[t] = fmaxf(a, 0.f);
    __syncthreads();
    if (t < 32) {
        float a2 = bc2[t];
        #pragma unroll 8
        for (int i = 0; i < 64; ++i) a2 += c1[i] * Wc2[i * 32 + t];
        c2[t] = fmaxf(a2, 0.f);
    }
    __syncthreads();
    float p = (t < 32) ? c2[t] * Wc3[t] : 0.f;
    #pragma unroll
    for (int m = 1; m < 64; m <<= 1) p += __shfl_xor(p, m);
    const float cons = 1.f / (1.f + __expf(-(p + bc3[0])));

    float sum = s0 + s1;
    float sq  = s0 * s0 + s1 * s1;
    float wsm = s0 * v0 + s1 * v1;
    float na  = (s0 > 0.1f ? 1.f : 0.f) + (s1 > 0.1f ? 1.f : 0.f);
    #pragma unroll
    for (int m = 1; m < 64; m <<= 1) {
        sum += __shfl_xor(sum, m); sq += __shfl_xor(sq, m);
        wsm += __shfl_xor(wsm, m); na += __shfl_xor(na, m);
    }
    if (t == 0) {
        const float mean = sum * (1.f / 128.f);
        float var = (sq - 128.f * mean * mean) * (1.f / 127.f);
        var = fmaxf(var, 0.f);
        const float agree = 1.f - sqrtf(var) / (mean + 1e-8f);
        out[b]        = cons * wsm;
        out[1024 + b] = (cons > 0.95f) ? 1.f : 0.f;
        out[2048 + b] = agree;
        out[3072 + b] = cons;
        out[4097 + b] = na;
    }
}

__global__ __launch_bounds__(256)
void attnmean_kernel(const float* __restrict__ bpart, float* __restrict__ out)
{
    __shared__ float red[4];
    const int t = threadIdx.x;
    const int lane = t & 63, wid = t >> 6;
    float s = bpart[t] + bpart[256 + t] + bpart[512 + t] + bpart[768 + t];
    #pragma unroll
    for (int m = 1; m < 64; m <<= 1) s += __shfl_xor(s, m);
    if (lane == 0) red[wid] = s;
    __syncthreads();
    if (t == 0) out[4096] = (red[0] + red[1] + red[2] + red[3]) * (1.f / 131072.f);
}

extern "C" void kernel_launch(void* const* d_in, const int* in_sizes, int n_in,
                              void* d_out, int out_size, void* d_ws, size_t ws_size,
                              hipStream_t stream)
{
    const float* x    = (const float*)d_in[0];
    const float* fs   = (const float*)d_in[1];
    const float* dm   = (const float*)d_in[2];
    const float* W1   = (const float*)d_in[3];
    const float* b1   = (const float*)d_in[4];
    const float* g1   = (const float*)d_in[5];
    const float* be1  = (const float*)d_in[6];
    const float* W2   = (const float*)d_in[7];
    const float* b2   = (const float*)d_in[8];
    const float* g2   = (const float*)d_in[9];
    const float* be2  = (const float*)d_in[10];
    const float* W3   = (const float*)d_in[11];
    const float* b3   = (const float*)d_in[12];
    const float* Wr   = (const float*)d_in[13];
    const float* br   = (const float*)d_in[14];
    const float* Wa1  = (const float*)d_in[15];
    const float* ba1  = (const float*)d_in[16];
    const float* Wa2  = (const float*)d_in[17];
    const float* ba2  = (const float*)d_in[18];
    const float* Wa3  = (const float*)d_in[19];
    const float* ba3  = (const float*)d_in[20];
    const float* Wqkv = (const float*)d_in[21];
    const float* bqkv = (const float*)d_in[22];
    // d_in[23]=Wo, d_in[24]=bo unused downstream
    const float* Wc1  = (const float*)d_in[25];
    const float* bc1  = (const float*)d_in[26];
    const float* Wc2  = (const float*)d_in[27];
    const float* bc2  = (const float*)d_in[28];
    const float* Wc3  = (const float*)d_in[29];
    const float* bc3  = (const float*)d_in[30];

    float* out = (float*)d_out;
    char*  ws8 = (char*)d_ws;
    unsigned short* enc_bf = (unsigned short*)ws8;             // 16 MB
    float* scores = (float*)(ws8 + 16777216);                  // 512 KB  [u][B]
    float* smean  = (float*)(ws8 + 17301504);                  // 512 KB
    float* bpart  = (float*)(ws8 + 17825792);                  // 4 KB
    unsigned short* xb    = (unsigned short*)(ws8 + 17829888); // 512 KB
    unsigned short* W1t   = (unsigned short*)(ws8 + 18354176); // 16 MB
    unsigned short* W2t   = (unsigned short*)(ws8 + 35131392); // 8 MB
    unsigned short* W3t   = (unsigned short*)(ws8 + 43520000); // 2 MB
    unsigned short* Wrt   = (unsigned short*)(ws8 + 45617152); // 1 MB
    unsigned short* wqkvb = (unsigned short*)(ws8 + 46665728); // 16 KB
    unsigned short* Wa1t  = (unsigned short*)(ws8 + 46682112); // 1 MB (hi+lo)
    unsigned short* Wa2t  = (unsigned short*)(ws8 + 47730688); // 256 KB (hi+lo)

    prep_kernel<<<3716, 256, 0, stream>>>(W1, W2, W3, Wr, Wa1, Wa2, x, Wqkv,
                                          W1t, W2t, W3t, Wrt, Wa1t, Wa2t, xb, wqkvb);
    fused_mfma<<<2048, 256, 0, stream>>>(xb, W1t, W2t, W3t, Wrt, Wa1t, Wa2t, fs, dm,
                                         b1, g1, be1, b2, g2, be2, b3, br,
                                         ba1, ba2, Wa3, ba3,
                                         enc_bf, scores);
    attn_kernel<<<1024, 256, 0, stream>>>(enc_bf, wqkvb, bqkv, smean, bpart);
    final_kernel<<<1024, 64, 0, stream>>>(scores, smean, Wc1, bc1, Wc2, bc2, Wc3, bc3, out);
    attnmean_kernel<<<1, 256, 0, stream>>>(bpart, out);
}

// Round 12
// 121.349 us; speedup vs baseline: 1.2280x; 1.0007x over previous
//
#include <hip/hip_runtime.h>
#include <math.h>

// U=128, D=256, B=1024, E=64, H=8
// prep_kernel : f32 -> bf16 frag-tiled weights [n/16][k/32][16][32] + x/wqkv -> bf16
//               + Wa1/Wa2 hi/lo bf16-split frag-tiled planes
// fused_mfma  : big GEMMs via MFMA with DIRECT global B-fragments; LN reductions
//               via DPP (VALU, no LDS); tail via split-bf16 MFMA (fp32-accurate).
// attn_kernel : MFMA Q/K proj + per-head MFMA S + DPP softmax + column sums
// final/attnmean: outputs

typedef float f32x4 __attribute__((ext_vector_type(4)));
typedef int   i32x4 __attribute__((ext_vector_type(4)));

__device__ __forceinline__ void mfma_bf16(f32x4& c, i32x4 a, i32x4 b) {
    asm("v_mfma_f32_16x16x32_bf16 %0, %1, %2, %0" : "+v"(c) : "v"(a), "v"(b));
}

__device__ __forceinline__ void gl_lds16(const void* g, void* l) {
    __builtin_amdgcn_global_load_lds(
        (const __attribute__((address_space(1))) unsigned int*)g,
        (__attribute__((address_space(3))) unsigned int*)l, 16, 0, 0);
}

__device__ __forceinline__ unsigned short f2bf(float v) {
    union { __bf16 b; unsigned short u; } cv;
    cv.b = (__bf16)v;
    return cv.u;
}
__device__ __forceinline__ float bf2f(unsigned short u) {
    union { unsigned int i; float f; } c; c.i = (unsigned int)u << 16; return c.f;
}

// sum over each 16-lane group via DPP (pure VALU, no LDS pipe):
// xor1 (quad_perm 1,0,3,2) + xor2 (quad_perm 2,3,0,1) + row_ror:4 + row_ror:8
__device__ __forceinline__ float red16(float v) {
    int x;
    x = __builtin_amdgcn_update_dpp(0, __float_as_int(v), 0xB1, 0xF, 0xF, true);
    v += __int_as_float(x);
    x = __builtin_amdgcn_update_dpp(0, __float_as_int(v), 0x4E, 0xF, 0xF, true);
    v += __int_as_float(x);
    x = __builtin_amdgcn_update_dpp(0, __float_as_int(v), 0x124, 0xF, 0xF, true);
    v += __int_as_float(x);
    x = __builtin_amdgcn_update_dpp(0, __float_as_int(v), 0x128, 0xF, 0xF, true);
    v += __int_as_float(x);
    return v;
}

// ---------------- prep: convert + frag-tile weights to bf16 ----------------
__global__ __launch_bounds__(256)
void prep_kernel(const float* __restrict__ W1, const float* __restrict__ W2,
                 const float* __restrict__ W3, const float* __restrict__ Wr,
                 const float* __restrict__ Wa1, const float* __restrict__ Wa2,
                 const float* __restrict__ x, const float* __restrict__ Wqkv,
                 unsigned short* __restrict__ W1t, unsigned short* __restrict__ W2t,
                 unsigned short* __restrict__ W3t, unsigned short* __restrict__ Wrt,
                 unsigned short* __restrict__ Wa1t, unsigned short* __restrict__ Wa2t,
                 unsigned short* __restrict__ xb, unsigned short* __restrict__ wqkvb)
{
    const int bid = blockIdx.x, t = threadIdx.x;
    if (bid >= 3588) {  // Wa1/Wa2 hi/lo split + frag-tile, one u per block
        const int uu = bid - 3588;
        #pragma unroll
        for (int i = 0; i < 8; ++i) {
            const int e = t * 8 + i;            // 0..2047
            const int k = e >> 5, n = e & 31;   // Wa1 [64 k][32 n]
            const float v = Wa1[(size_t)uu * 2048 + k * 32 + n];
            const unsigned short h = f2bf(v);
            const unsigned short l = f2bf(v - bf2f(h));
            const size_t d = (size_t)uu * 4096 +
                (((n >> 4) * 2 + (k >> 5)) * 512 + (n & 15) * 32 + (k & 31));
            Wa1t[d] = h; Wa1t[d + 2048] = l;
        }
        #pragma unroll
        for (int i = 0; i < 2; ++i) {
            const int e = t * 2 + i;            // 0..511
            const int k = e >> 4, n = e & 15;   // Wa2 [32 k][16 n]
            const float v = Wa2[(size_t)uu * 512 + k * 16 + n];
            const unsigned short h = f2bf(v);
            const unsigned short l = f2bf(v - bf2f(h));
            const size_t d = (size_t)uu * 1024 + n * 32 + k;
            Wa2t[d] = h; Wa2t[d + 512] = l;
        }
        return;
    }
    if (bid >= 3456) {  // plain convert, no transpose
        const float* src; unsigned short* dst; int base;
        if (bid >= 3584) { src = Wqkv; dst = wqkvb; base = (bid - 3584) * 2048 + t * 8; }
        else             { src = x;    dst = xb;    base = (bid - 3456) * 2048 + t * 8; }
        const float4 v0 = *(const float4*)(src + base);
        const float4 v1 = *(const float4*)(src + base + 4);
        __align__(16) unsigned short o[8];
        o[0]=f2bf(v0.x); o[1]=f2bf(v0.y); o[2]=f2bf(v0.z); o[3]=f2bf(v0.w);
        o[4]=f2bf(v1.x); o[5]=f2bf(v1.y); o[6]=f2bf(v1.z); o[7]=f2bf(v1.w);
        *(uint4*)(dst + base) = *(const uint4*)o;
        return;
    }
    const float* src; unsigned short* dst; int u, k0, n0, N, ktiles;
    if (bid < 2048)      { u = bid >> 4;        int tl = bid & 15;       k0 = (tl>>2)*64; n0 = (tl&3)*64; N=256; ktiles=8; src = W1 + (size_t)u*65536; dst = W1t + (size_t)u*65536; }
    else if (bid < 3072) { int b2 = bid - 2048; u = b2 >> 3; int tl = b2 & 7; k0 = (tl>>1)*64; n0 = (tl&1)*64; N=128; ktiles=8; src = W2 + (size_t)u*32768; dst = W2t + (size_t)u*32768; }
    else if (bid < 3328) { int b3 = bid - 3072; u = b3 >> 1; int tl = b3 & 1; k0 = tl*64;      n0 = 0;         N=64;  ktiles=4; src = W3 + (size_t)u*8192;  dst = W3t + (size_t)u*8192;  }
    else                 { u = bid - 3328;      k0 = 0; n0 = 0;                                 N=64;  ktiles=2; src = Wr + (size_t)u*4096;  dst = Wrt + (size_t)u*4096;  }

    __shared__ unsigned short tile[64 * 65];
    #pragma unroll
    for (int i = 0; i < 16; ++i) {
        const int e = i * 256 + t;
        const int kk = e >> 6, nn = e & 63;
        tile[kk * 65 + nn] = f2bf(src[(size_t)(k0 + kk) * N + n0 + nn]);
    }
    __syncthreads();
    #pragma unroll
    for (int i = 0; i < 16; ++i) {
        const int e = i * 256 + t;
        const int nn = e >> 6, kk = e & 63;
        const int n = n0 + nn, k = k0 + kk;
        dst[(size_t)(((n >> 4) * ktiles + (k >> 5)) * 512 + (n & 15) * 32 + (k & 31))] = tile[kk * 65 + nn];
    }
}

// ---------------- fused universe chain ----------------
__global__ __launch_bounds__(256, 4)
void fused_mfma(const unsigned short* __restrict__ xb,
                const unsigned short* __restrict__ W1t, const unsigned short* __restrict__ W2t,
                const unsigned short* __restrict__ W3t, const unsigned short* __restrict__ Wrt,
                const unsigned short* __restrict__ Wa1t, const unsigned short* __restrict__ Wa2t,
                const float* __restrict__ fs, const float* __restrict__ dm,
                const float* __restrict__ b1, const float* __restrict__ g1, const float* __restrict__ be1,
                const float* __restrict__ b2, const float* __restrict__ g2, const float* __restrict__ be2,
                const float* __restrict__ b3, const float* __restrict__ br,
                const float* __restrict__ ba1, const float* __restrict__ ba2,
                const float* __restrict__ Wa3, const float* __restrict__ ba3,
                unsigned short* __restrict__ enc_bfg, float* __restrict__ scores_g)
{
    // LDS: [0,32768) A_x/H1 -> H2 [0,16K) -> enc [0,8K) ; z_hi [8192,16384),
    // z_lo [16384,24576) ; a1_hi [24576,28672), a1_lo [28672,32768) ;
    // stats at [36864,39680)
    __shared__ __align__(128) char sm[39680];
    char* R0 = sm;
    float* pS = (float*)(sm + 36864);
    float* pQ = (float*)(sm + 37888);
    float2* rst = (float2*)(sm + 38912);
    float* dmis = (float*)(sm + 39424);

    const int t = threadIdx.x;
    const int wid = t >> 6, lane = t & 63, l15 = lane & 15, lk = lane >> 4;
    const int swz = (l15 & 7) << 4;
    const int lo64 = l15 * 64 + lk * 16;
    const int bx = blockIdx.x;
    const int xcd = bx & 7, idx = bx >> 3;
    const int u = ((idx >> 4) << 3) + xcd;
    const int b0 = (idx & 15) * 64;

    const float corru = fs[u] * 137.036f;
    const float dmu = dm[u];

    const char* xbase = (const char*)xb + (size_t)b0 * 512;
    const char* w1u = (const char*)W1t + (size_t)u * 131072;
    const char* w2u = (const char*)W2t + (size_t)u * 65536;
    const char* w3u = (const char*)W3t + (size_t)u * 16384;
    const char* wru = (const char*)Wrt + (size_t)u * 8192;
    const char* wa1u = (const char*)Wa1t + (size_t)u * 8192;
    const char* wa2u = (const char*)Wa2t + (size_t)u * 2048;

    #pragma unroll
    for (int it = 0; it < 8; ++it) {
        const int d = it * 4096 + t * 16;
        const int s = d ^ (((d >> 9) & 7) << 4);
        gl_lds16(xbase + s, R0 + it * 4096 + wid * 1024);
    }
    __syncthreads();  // B0

    // ===== GEMM1: [64][256] = A_x @ W1t, K=256, B direct + reg double-buffer =====
    const f32x4 z4 = {0.f, 0.f, 0.f, 0.f};
    f32x4 acc[4][4];
    #pragma unroll
    for (int mi = 0; mi < 4; ++mi)
        #pragma unroll
        for (int ni = 0; ni < 4; ++ni) acc[mi][ni] = z4;

    {
        i32x4 bfP[4], bfQ[4];
        #pragma unroll
        for (int ni = 0; ni < 4; ++ni)
            bfP[ni] = *(const i32x4*)(w1u + ((wid * 4 + ni) * 8 + 0) * 1024 + lo64);
        #pragma unroll
        for (int kt = 0; kt < 8; ++kt) {
            if (kt < 7) {
                #pragma unroll
                for (int ni = 0; ni < 4; ++ni)
                    ((kt & 1) ? bfP : bfQ)[ni] =
                        *(const i32x4*)(w1u + ((wid * 4 + ni) * 8 + kt + 1) * 1024 + lo64);
            }
            i32x4 af[4];
            const int p = kt >> 1, ks = kt & 1;
            #pragma unroll
            for (int mi = 0; mi < 4; ++mi) {
                const int off = ((mi * 16 + l15) << 9) + p * 128 + ks * 64 + lk * 16;
                af[mi] = *(const i32x4*)(R0 + (off ^ swz));
            }
            #pragma unroll
            for (int mi = 0; mi < 4; ++mi)
                #pragma unroll
                for (int ni = 0; ni < 4; ++ni)
                    mfma_bf16(acc[mi][ni], af[mi], ((kt & 1) ? bfQ : bfP)[ni]);
        }
    }

    // ===== LN1 + relu -> H1 bf16 [64][512B] swz (DPP reductions) =====
    float bb[4], gg[4], ee[4];
    #pragma unroll
    for (int ni = 0; ni < 4; ++ni) {
        const int c = wid * 64 + ni * 16 + l15;
        bb[ni] = b1[u * 256 + c]; gg[ni] = g1[u * 256 + c]; ee[ni] = be1[u * 256 + c];
    }
    #pragma unroll
    for (int mi = 0; mi < 4; ++mi) {
        #pragma unroll
        for (int j = 0; j < 4; ++j) {
            float s = 0.f, q = 0.f;
            #pragma unroll
            for (int ni = 0; ni < 4; ++ni) {
                const float h = acc[mi][ni][j] * corru + bb[ni];
                acc[mi][ni][j] = h;
                s += h; q += h * h;
            }
            s = red16(s); q = red16(q);
            if (l15 == 0) {
                const int r = mi * 16 + lk * 4 + j;
                pS[wid * 64 + r] = s; pQ[wid * 64 + r] = q;
            }
        }
    }
    __syncthreads();  // B1
    if (t < 64) {
        const float s = pS[t] + pS[64 + t] + pS[128 + t] + pS[192 + t];
        const float q = pQ[t] + pQ[64 + t] + pQ[128 + t] + pQ[192 + t];
        const float mean = s * (1.f / 256.f);
        const float var = fmaxf(q * (1.f / 256.f) - mean * mean, 0.f);
        rst[t] = make_float2(mean, rsqrtf(var + 1e-5f));
    }
    __syncthreads();  // B2
    #pragma unroll
    for (int mi = 0; mi < 4; ++mi) {
        #pragma unroll
        for (int j = 0; j < 4; ++j) {
            const int r = mi * 16 + lk * 4 + j;
            const float2 st = rst[r];
            #pragma unroll
            for (int ni = 0; ni < 4; ++ni) {
                const float h = fmaxf((acc[mi][ni][j] - st.x) * st.y * gg[ni] + ee[ni], 0.f);
                const int c = wid * 64 + ni * 16 + l15;
                const int off = (r << 9) + c * 2;
                *(__bf16*)(R0 + (off ^ ((r & 7) << 4))) = (__bf16)h;
            }
        }
    }
    __syncthreads();  // B3: H1 ready

    // ===== GEMM2: [64][128] = H1 @ W2t, K=256, reg double-buffer =====
    f32x4 acc2[4][2];
    #pragma unroll
    for (int mi = 0; mi < 4; ++mi) { acc2[mi][0] = z4; acc2[mi][1] = z4; }
    {
        i32x4 bfP[2], bfQ[2];
        #pragma unroll
        for (int ni = 0; ni < 2; ++ni)
            bfP[ni] = *(const i32x4*)(w2u + ((wid * 2 + ni) * 8 + 0) * 1024 + lo64);
        #pragma unroll
        for (int kt = 0; kt < 8; ++kt) {
            if (kt < 7) {
                #pragma unroll
                for (int ni = 0; ni < 2; ++ni)
                    ((kt & 1) ? bfP : bfQ)[ni] =
                        *(const i32x4*)(w2u + ((wid * 2 + ni) * 8 + kt + 1) * 1024 + lo64);
            }
            i32x4 af[4];
            const int p = kt >> 1, ks = kt & 1;
            #pragma unroll
            for (int mi = 0; mi < 4; ++mi) {
                const int off = ((mi * 16 + l15) << 9) + p * 128 + ks * 64 + lk * 16;
                af[mi] = *(const i32x4*)(R0 + (off ^ swz));
            }
            #pragma unroll
            for (int mi = 0; mi < 4; ++mi)
                #pragma unroll
                for (int ni = 0; ni < 2; ++ni)
                    mfma_bf16(acc2[mi][ni], af[mi], ((kt & 1) ? bfQ : bfP)[ni]);
        }
    }

    // ===== LN2 + relu -> H2 bf16 [64][256B] at [0,16K) (DPP reductions) =====
    float bb2[2], gg2[2], ee2[2];
    #pragma unroll
    for (int ni = 0; ni < 2; ++ni) {
        const int c = wid * 32 + ni * 16 + l15;
        bb2[ni] = b2[u * 128 + c]; gg2[ni] = g2[u * 128 + c]; ee2[ni] = be2[u * 128 + c];
    }
    #pragma unroll
    for (int mi = 0; mi < 4; ++mi) {
        #pragma unroll
        for (int j = 0; j < 4; ++j) {
            float s = 0.f, q = 0.f;
            #pragma unroll
            for (int ni = 0; ni < 2; ++ni) {
                const float h = acc2[mi][ni][j] + bb2[ni];
                acc2[mi][ni][j] = h;
                s += h; q += h * h;
            }
            s = red16(s); q = red16(q);
            if (l15 == 0) {
                const int r = mi * 16 + lk * 4 + j;
                pS[wid * 64 + r] = s; pQ[wid * 64 + r] = q;
            }
        }
    }
    __syncthreads();  // B4
    if (t < 64) {
        const float s = pS[t] + pS[64 + t] + pS[128 + t] + pS[192 + t];
        const float q = pQ[t] + pQ[64 + t] + pQ[128 + t] + pQ[192 + t];
        const float mean = s * (1.f / 128.f);
        const float var = fmaxf(q * (1.f / 128.f) - mean * mean, 0.f);
        rst[t] = make_float2(mean, rsqrtf(var + 1e-5f));
    }
    __syncthreads();  // B5
    #pragma unroll
    for (int mi = 0; mi < 4; ++mi) {
        #pragma unroll
        for (int j = 0; j < 4; ++j) {
            const int r = mi * 16 + lk * 4 + j;
            const float2 st = rst[r];
            #pragma unroll
            for (int ni = 0; ni < 2; ++ni) {
                const float h = fmaxf((acc2[mi][ni][j] - st.x) * st.y * gg2[ni] + ee2[ni], 0.f);
                const int c = wid * 32 + ni * 16 + l15;
                const int off = (r << 8) + c * 2;
                *(__bf16*)(R0 + (off ^ ((r & 7) << 4))) = (__bf16)h;
            }
        }
    }
    __syncthreads();  // B6: H2 ready

    // ===== GEMM3: enc [64][64] = H2 @ W3t, K=128 =====
    f32x4 acc3[4];
    #pragma unroll
    for (int mi = 0; mi < 4; ++mi) acc3[mi] = z4;
    #pragma unroll
    for (int ks = 0; ks < 4; ++ks) {
        const i32x4 bfr = *(const i32x4*)(w3u + (wid * 4 + ks) * 1024 + lo64);
        #pragma unroll
        for (int mi = 0; mi < 4; ++mi) {
            const int off = ((mi * 16 + l15) << 8) + ks * 64 + lk * 16;
            const i32x4 afm = *(const i32x4*)(R0 + (off ^ swz));
            mfma_bf16(acc3[mi], afm, bfr);
        }
    }
    // epilogue: +b3 (f32 encr regs), sumsq partials via DPP
    const int c16 = wid * 16 + l15;
    const float b3v = b3[u * 64 + c16];
    float encr[4][4];
    #pragma unroll
    for (int mi = 0; mi < 4; ++mi) {
        #pragma unroll
        for (int j = 0; j < 4; ++j) {
            const float e = acc3[mi][j] + b3v;
            encr[mi][j] = e;
            const float q = red16(e * e);
            if (l15 == 0) {
                const int r = mi * 16 + lk * 4 + j;
                pQ[wid * 64 + r] = q;
            }
        }
    }
    __syncthreads();  // B7: all GEMM3 H2-reads done, partials visible
    if (t < 64) {
        const float q = pQ[t] + pQ[64 + t] + pQ[128 + t] + pQ[192 + t];
        dmis[t] = tanhf(dmu * q);
    }
    // enc bf16 -> [0,8192)
    #pragma unroll
    for (int mi = 0; mi < 4; ++mi) {
        #pragma unroll
        for (int j = 0; j < 4; ++j) {
            const int r = mi * 16 + lk * 4 + j;
            const int off = (r << 7) + c16 * 2;
            *(__bf16*)(R0 + (off ^ ((r & 7) << 4))) = (__bf16)encr[mi][j];
        }
    }
    __syncthreads();  // B8: enc + dmis ready

    // coalesced enc global store from LDS: line-aligned 128B rows
    {
        const int c8 = t & 7;
        #pragma unroll
        for (int pass = 0; pass < 2; ++pass) {
            const int row = pass * 32 + (t >> 3);
            const int off = (row << 7) + c8 * 16;
            const uint4 v = *(const uint4*)(R0 + (off ^ ((row & 7) << 4)));
            *(uint4*)((char*)enc_bfg + (((size_t)(b0 + row) * 128 + u) << 7) + c8 * 16) = v;
        }
    }

    // ===== Wr: re [64][64] = enc_bf @ Wrt, K=64; z -> bf16 hi/lo planes =====
    f32x4 accR[4];
    #pragma unroll
    for (int mi = 0; mi < 4; ++mi) accR[mi] = z4;
    #pragma unroll
    for (int ks = 0; ks < 2; ++ks) {
        const i32x4 bfr = *(const i32x4*)(wru + (wid * 2 + ks) * 1024 + lo64);
        #pragma unroll
        for (int mi = 0; mi < 4; ++mi) {
            const int off = ((mi * 16 + l15) << 7) + ks * 64 + lk * 16;
            const i32x4 afm = *(const i32x4*)(R0 + (off ^ swz));
            mfma_bf16(accR[mi], afm, bfr);
        }
    }
    const float brv = br[u * 64 + c16];
    #pragma unroll
    for (int mi = 0; mi < 4; ++mi) {
        #pragma unroll
        for (int j = 0; j < 4; ++j) {
            const int r = mi * 16 + lk * 4 + j;
            const float zv = accR[mi][j] + brv + dmis[r] * encr[mi][j];
            const __bf16 zh = (__bf16)zv;
            const __bf16 zl = (__bf16)(zv - (float)zh);
            const int off = (r << 7) + c16 * 2;
            const int sw = (r & 7) << 4;
            *(__bf16*)(R0 + 8192 + (off ^ sw)) = zh;
            *(__bf16*)(R0 + 16384 + (off ^ sw)) = zl;
        }
    }
    __syncthreads();  // B9: z planes ready, enc reads done

    // ===== a1 = relu(z@Wa1 + ba1), split-bf16 MFMA (fp32-accurate) =====
    // wave w owns rows w*16..w*16+15, cols 0..31
    f32x4 accA[2] = {z4, z4};
    #pragma unroll
    for (int ks = 0; ks < 2; ++ks) {
        const int zoff = ((wid * 16 + l15) << 7) + ks * 64 + lk * 16;
        const int zsw = (l15 & 7) << 4;
        const i32x4 zh = *(const i32x4*)(R0 + 8192 + (zoff ^ zsw));
        const i32x4 zl = *(const i32x4*)(R0 + 16384 + (zoff ^ zsw));
        #pragma unroll
        for (int ni = 0; ni < 2; ++ni) {
            const i32x4 bh = *(const i32x4*)(wa1u + (ni * 2 + ks) * 1024 + lo64);
            const i32x4 bl = *(const i32x4*)(wa1u + 4096 + (ni * 2 + ks) * 1024 + lo64);
            mfma_bf16(accA[ni], zh, bh);
            mfma_bf16(accA[ni], zl, bh);
            mfma_bf16(accA[ni], zh, bl);
        }
    }
    // relu+bias, split a1 hi/lo -> LDS [64][64B] planes (same-wave RAW, no barrier)
    #pragma unroll
    for (int ni = 0; ni < 2; ++ni) {
        const float bav = ba1[u * 32 + ni * 16 + l15];
        #pragma unroll
        for (int j = 0; j < 4; ++j) {
            const int row = wid * 16 + lk * 4 + j;
            const float av = fmaxf(accA[ni][j] + bav, 0.f);
            const __bf16 ah = (__bf16)av;
            const __bf16 al = (__bf16)(av - (float)ah);
            const int off = (row << 6) + (ni * 16 + l15) * 2;
            const int sw = (row & 3) << 4;
            *(__bf16*)(R0 + 24576 + (off ^ sw)) = ah;
            *(__bf16*)(R0 + 28672 + (off ^ sw)) = al;
        }
    }

    // ===== a2 = relu(a1@Wa2 + ba2), split-bf16 MFMA; scores via DPP dot =====
    f32x4 accB = z4;
    {
        const int row = wid * 16 + l15;
        const int aoff = (row << 6) + lk * 16;
        const int asw = (l15 & 3) << 4;
        const i32x4 ah = *(const i32x4*)(R0 + 24576 + (aoff ^ asw));
        const i32x4 al = *(const i32x4*)(R0 + 28672 + (aoff ^ asw));
        const i32x4 bh = *(const i32x4*)(wa2u + lo64);
        const i32x4 bl = *(const i32x4*)(wa2u + 1024 + lo64);
        mfma_bf16(accB, ah, bh);
        mfma_bf16(accB, al, bh);
        mfma_bf16(accB, ah, bl);
    }
    const float ba2v = ba2[u * 16 + l15];
    const float wa3v = Wa3[u * 16 + l15];
    const float ba3u = ba3[u];
    #pragma unroll
    for (int j = 0; j < 4; ++j) {
        const float vsum = red16(fmaxf(accB[j] + ba2v, 0.f) * wa3v);
        if (l15 == 0) {
            const int r = wid * 16 + lk * 4 + j;
            scores_g[(size_t)u * 1024 + b0 + r] = 1.f / (1.f + __expf(-(vsum + ba3u)));
        }
    }
}

// ---------------- attention: MFMA proj + per-head MFMA S + DPP softmax ----------------
__global__ __launch_bounds__(256, 3)
void attn_kernel(const unsigned short* __restrict__ enc_bf,
                 const unsigned short* __restrict__ wqkv_bf,
                 const float* __restrict__ bqkv, float* __restrict__ smean,
                 float* __restrict__ bpart)
{
    __shared__ __align__(128) char sm[34944];
    char* Qp = sm;
    char* Ks = sm + 16384;
    float* colp = (float*)(sm + 32832);
    char* ENCs = sm;
    char* WQs  = sm + 16384;

    const int t = threadIdx.x;
    const int wid = t >> 6, lane = t & 63, l15 = lane & 15, lk = lane >> 4;
    const int swz = (l15 & 7) << 4;
    const int b = blockIdx.x;

    const char* eb = (const char*)(enc_bf + (size_t)b * 8192);
    #pragma unroll
    for (int it = 0; it < 4; ++it) {
        const int d = it * 4096 + t * 16;
        const int s = d ^ (((d >> 7) & 7) << 4);
        gl_lds16(eb + s, ENCs + it * 4096 + wid * 1024);
    }
    const char* wb = (const char*)wqkv_bf;
    #pragma unroll
    for (int it = 0; it < 4; ++it) {
        const int d = it * 4096 + t * 16;
        const int s = d ^ (((d >> 7) & 7) << 4);
        gl_lds16(wb + s, WQs + it * 4096 + wid * 1024);
    }
    __syncthreads();

    const f32x4 z4 = {0.f,0.f,0.f,0.f};
    f32x4 aq[2][4], ak[2][4];
    #pragma unroll
    for (int mi = 0; mi < 2; ++mi)
        #pragma unroll
        for (int ni = 0; ni < 4; ++ni) { aq[mi][ni] = z4; ak[mi][ni] = z4; }

    i32x4 af[2][2];
    #pragma unroll
    for (int mi = 0; mi < 2; ++mi)
        #pragma unroll
        for (int ks = 0; ks < 2; ++ks) {
            const int off = ((wid * 32 + mi * 16 + l15) << 7) + ks * 64 + lk * 16;
            af[mi][ks] = *(const i32x4*)(ENCs + (off ^ swz));
        }
    #pragma unroll
    for (int ni = 0; ni < 4; ++ni)
        #pragma unroll
        for (int ks = 0; ks < 2; ++ks) {
            const int offq = ((ni * 16 + l15) << 7) + ks * 64 + lk * 16;
            const i32x4 bq = *(const i32x4*)(WQs + (offq ^ swz));
            mfma_bf16(aq[0][ni], af[0][ks], bq);
            mfma_bf16(aq[1][ni], af[1][ks], bq);
            const i32x4 bk = *(const i32x4*)(WQs + ((offq + 8192) ^ swz));
            mfma_bf16(ak[0][ni], af[0][ks], bk);
            mfma_bf16(ak[1][ni], af[1][ks], bk);
        }

    float bqv[4], bkv[4];
    #pragma unroll
    for (int ni = 0; ni < 4; ++ni) {
        bqv[ni] = bqkv[ni * 16 + l15];
        bkv[ni] = bqkv[64 + ni * 16 + l15];
    }
    __syncthreads();

    {
        const int par = t >> 7, row = t & 127;
        char* base = Qp + par * 8192 + row * 64;
        *(f32x4*)(base + 16) = z4;
        *(f32x4*)(base + 32) = z4;
        *(f32x4*)(base + 48) = z4;
    }
    #pragma unroll
    for (int mi = 0; mi < 2; ++mi)
        #pragma unroll
        for (int ni = 0; ni < 4; ++ni)
            #pragma unroll
            for (int j = 0; j < 4; ++j) {
                const int row = wid * 32 + mi * 16 + lk * 4 + j;
                const int f = ni * 16 + l15;
                const int off = row * 128 + f * 2;
                *(__bf16*)(Ks + (off ^ ((row & 7) << 4))) = (__bf16)(ak[mi][ni][j] + bkv[ni]);
            }
    __syncthreads();

    const float qscale = 0.35355339059327373f;
    float cp[8] = {0.f,0.f,0.f,0.f,0.f,0.f,0.f,0.f};

    #pragma unroll
    for (int p = 0; p < 4; ++p) {
        #pragma unroll
        for (int mi = 0; mi < 2; ++mi)
            #pragma unroll
            for (int j = 0; j < 4; ++j) {
                const int row = wid * 32 + mi * 16 + lk * 4 + j;
                *(__bf16*)(Qp + (l15 >> 3) * 8192 + row * 64 + (l15 & 7) * 2) =
                    (__bf16)((aq[mi][p][j] + bqv[p]) * qscale);
            }
        __syncthreads();

        #pragma unroll 1
        for (int par = 0; par < 2; ++par) {
            const int h = p * 2 + par;
            const i32x4 aQ0 = *(const i32x4*)(Qp + par * 8192 + (wid * 32 + l15) * 64 + lk * 16);
            const i32x4 aQ1 = *(const i32x4*)(Qp + par * 8192 + (wid * 32 + 16 + l15) * 64 + lk * 16);
            f32x4 accS[2][8];
            #pragma unroll
            for (int ci = 0; ci < 8; ++ci) { accS[0][ci] = z4; accS[1][ci] = z4; }
            #pragma unroll
            for (int ci = 0; ci < 8; ++ci) {
                const int col = ci * 16 + l15;
                const i32x4 bK = *(const i32x4*)(Ks + ((col * 128 + ((h + lk) & 7) * 16) ^ ((col & 7) << 4)));
                mfma_bf16(accS[0][ci], aQ0, bK);
                mfma_bf16(accS[1][ci], aQ1, bK);
            }
            #pragma unroll
            for (int mi = 0; mi < 2; ++mi)
                #pragma unroll
                for (int j = 0; j < 4; ++j) {
                    float e[8];
                    float z = 0.f;
                    #pragma unroll
                    for (int ci = 0; ci < 8; ++ci) { e[ci] = __expf(accS[mi][ci][j]); z += e[ci]; }
                    z = red16(z);
                    const float zi = 1.f / z;
                    #pragma unroll
                    for (int ci = 0; ci < 8; ++ci) cp[ci] += e[ci] * zi;
                }
        }
        __syncthreads();
    }

    #pragma unroll
    for (int ci = 0; ci < 8; ++ci) {
        cp[ci] += __shfl_xor(cp[ci], 16);
        cp[ci] += __shfl_xor(cp[ci], 32);
    }
    if (lk == 0) {
        #pragma unroll
        for (int ci = 0; ci < 8; ++ci)
            colp[wid * 128 + ci * 16 + l15] = cp[ci];
    }
    __syncthreads();
    float v = 0.f;
    if (t < 128) {
        v = colp[t] + colp[128 + t] + colp[256 + t] + colp[384 + t];
        smean[(size_t)b * 128 + t] = v * (1.f / 1024.f);
    }
    #pragma unroll
    for (int m = 1; m < 64; m <<= 1) v += __shfl_xor(v, m);
    if (lane == 0) colp[512 + wid] = v;
    __syncthreads();
    if (t == 0)
        bpart[b] = (colp[512] + colp[513] + colp[514] + colp[515]) * (1.f / 1024.f);
}

__global__ __launch_bounds__(64)
void final_kernel(const float* __restrict__ scores_g, const float* __restrict__ smean,
                  const float* __restrict__ Wc1, const float* __restrict__ bc1,
                  const float* __restrict__ Wc2, const float* __restrict__ bc2,
                  const float* __restrict__ Wc3, const float* __restrict__ bc3,
                  float* __restrict__ out)
{
    __shared__ float sc[128];
    __shared__ float c1[64];
    __shared__ float c2[32];
    const int b = blockIdx.x, t = threadIdx.x;
    const float s0 = scores_g[(size_t)t * 1024 + b];
    const float s1 = scores_g[(size_t)(t + 64) * 1024 + b];
    sc[t] = s0; sc[64 + t] = s1;
    const float v0 = smean[(size_t)b * 128 + t];
    const float v1 = smean[(size_t)b * 128 + 64 + t];
    __syncthreads();
    float a = bc1[t];
    #pragma unroll 8
    for (int i = 0; i < 128; ++i) a += sc[i] * Wc1[i * 64 + t];
    c1[t] = fmaxf(a, 0.f);
    __syncthreads();
    if (t < 32) {
        float a2 = bc2[t];
        #pragma unroll 8
        for (int i = 0; i < 64; ++i) a2 += c1[i] * Wc2[i * 32 + t];
        c2[t] = fmaxf(a2, 0.f);
    }
    __syncthreads();
    float p = (t < 32) ? c2[t] * Wc3[t] : 0.f;
    #pragma unroll
    for (int m = 1; m < 64; m <<= 1) p += __shfl_xor(p, m);
    const float cons = 1.f / (1.f + __expf(-(p + bc3[0])));

    float sum = s0 + s1;
    float sq  = s0 * s0 + s1 * s1;
    float wsm = s0 * v0 + s1 * v1;
    float na  = (s0 > 0.1f ? 1.f : 0.f) + (s1 > 0.1f ? 1.f : 0.f);
    #pragma unroll
    for (int m = 1; m < 64; m <<= 1) {
        sum += __shfl_xor(sum, m); sq += __shfl_xor(sq, m);
        wsm += __shfl_xor(wsm, m); na += __shfl_xor(na, m);
    }
    if (t == 0) {
        const float mean = sum * (1.f / 128.f);
        float var = (sq - 128.f * mean * mean) * (1.f / 127.f);
        var = fmaxf(var, 0.f);
        const float agree = 1.f - sqrtf(var) / (mean + 1e-8f);
        out[b]        = cons * wsm;
        out[1024 + b] = (cons > 0.95f) ? 1.f : 0.f;
        out[2048 + b] = agree;
        out[3072 + b] = cons;
        out[4097 + b] = na;
    }
}

__global__ __launch_bounds__(256)
void attnmean_kernel(const float* __restrict__ bpart, float* __restrict__ out)
{
    __shared__ float red[4];
    const int t = threadIdx.x;
    const int lane = t & 63, wid = t >> 6;
    float s = bpart[t] + bpart[256 + t] + bpart[512 + t] + bpart[768 + t];
    #pragma unroll
    for (int m = 1; m < 64; m <<= 1) s += __shfl_xor(s, m);
    if (lane == 0) red[wid] = s;
    __syncthreads();
    if (t == 0) out[4096] = (red[0] + red[1] + red[2] + red[3]) * (1.f / 131072.f);
}

extern "C" void kernel_launch(void* const* d_in, const int* in_sizes, int n_in,
                              void* d_out, int out_size, void* d_ws, size_t ws_size,
                              hipStream_t stream)
{
    const float* x    = (const float*)d_in[0];
    const float* fs   = (const float*)d_in[1];
    const float* dm   = (const float*)d_in[2];
    const float* W1   = (const float*)d_in[3];
    const float* b1   = (const float*)d_in[4];
    const float* g1   = (const float*)d_in[5];
    const float* be1  = (const float*)d_in[6];
    const float* W2   = (const float*)d_in[7];
    const float* b2   = (const float*)d_in[8];
    const float* g2   = (const float*)d_in[9];
    const float* be2  = (const float*)d_in[10];
    const float* W3   = (const float*)d_in[11];
    const float* b3   = (const float*)d_in[12];
    const float* Wr   = (const float*)d_in[13];
    const float* br   = (const float*)d_in[14];
    const float* Wa1  = (const float*)d_in[15];
    const float* ba1  = (const float*)d_in[16];
    const float* Wa2  = (const float*)d_in[17];
    const float* ba2  = (const float*)d_in[18];
    const float* Wa3  = (const float*)d_in[19];
    const float* ba3  = (const float*)d_in[20];
    const float* Wqkv = (const float*)d_in[21];
    const float* bqkv = (const float*)d_in[22];
    // d_in[23]=Wo, d_in[24]=bo unused downstream
    const float* Wc1  = (const float*)d_in[25];
    const float* bc1  = (const float*)d_in[26];
    const float* Wc2  = (const float*)d_in[27];
    const float* bc2  = (const float*)d_in[28];
    const float* Wc3  = (const float*)d_in[29];
    const float* bc3  = (const float*)d_in[30];

    float* out = (float*)d_out;
    char*  ws8 = (char*)d_ws;
    unsigned short* enc_bf = (unsigned short*)ws8;             // 16 MB
    float* scores = (float*)(ws8 + 16777216);                  // 512 KB  [u][B]
    float* smean  = (float*)(ws8 + 17301504);                  // 512 KB
    float* bpart  = (float*)(ws8 + 17825792);                  // 4 KB
    unsigned short* xb    = (unsigned short*)(ws8 + 17829888); // 512 KB
    unsigned short* W1t   = (unsigned short*)(ws8 + 18354176); // 16 MB
    unsigned short* W2t   = (unsigned short*)(ws8 + 35131392); // 8 MB
    unsigned short* W3t   = (unsigned short*)(ws8 + 43520000); // 2 MB
    unsigned short* Wrt   = (unsigned short*)(ws8 + 45617152); // 1 MB
    unsigned short* wqkvb = (unsigned short*)(ws8 + 46665728); // 16 KB
    unsigned short* Wa1t  = (unsigned short*)(ws8 + 46682112); // 1 MB (hi+lo)
    unsigned short* Wa2t  = (unsigned short*)(ws8 + 47730688); // 256 KB (hi+lo)

    prep_kernel<<<3716, 256, 0, stream>>>(W1, W2, W3, Wr, Wa1, Wa2, x, Wqkv,
                                          W1t, W2t, W3t, Wrt, Wa1t, Wa2t, xb, wqkvb);
    fused_mfma<<<2048, 256, 0, stream>>>(xb, W1t, W2t, W3t, Wrt, Wa1t, Wa2t, fs, dm,
                                         b1, g1, be1, b2, g2, be2, b3, br,
                                         ba1, ba2, Wa3, ba3,
                                         enc_bf, scores);
    attn_kernel<<<1024, 256, 0, stream>>>(enc_bf, wqkvb, bqkv, smean, bpart);
    final_kernel<<<1024, 64, 0, stream>>>(scores, smean, Wc1, bc1, Wc2, bc2, Wc3, bc3, out);
    attnmean_kernel<<<1, 256, 0, stream>>>(bpart, out);
}